// Round 2
// baseline (198.994 us; speedup 1.0000x reference)
//
#include <hip/hip_runtime.h>

// ---------------------------------------------------------------------------
// 2-layer GCN forward (PyG GCNConv) on MI355X, round 8b (R8 resubmit; R8's
// bench died at container level with no kernel-attributable evidence).
//   out[d] = relu( p[d]*( sum_{s->d} p[s]*h[s] + p[d]*h[d] ) + b ),  h = x@W
// R8 changes vs R7:
//  - aggregate1 + gemm2 FUSED into gemm2_fused: h1 rows are computed
//    per-64-K-slice on the fly as the A-operand staging of the layer-2 GEMM
//    (BM=64, BN=256 single col-block so the gather happens exactly once).
//    Eliminates the 20.5MB h1b write + 41MB read and overlaps the 180MB
//    L3 gather with the W2 MFMAs. 5 dispatches instead of 6.
//  - everything else unchanged (ELL, BK=64 gemm1, prep).
// Floor analysis: agg traffic is L3-BW bound (~7 TB/s); prep is HBM-bound;
// harness fill+restores ~58 us of the timed window.
// ---------------------------------------------------------------------------

typedef __bf16 bf16x8 __attribute__((ext_vector_type(8)));
typedef float floatx4 __attribute__((ext_vector_type(4)));
typedef unsigned short ushort_t;
typedef unsigned int uint_t;

#define MAXD 32
#define CAP 40  // self + 32 ELL + pad-to-multiple-of-8 (pads: ps=0, col=self)

__device__ inline ushort_t f2bf(float f) {  // RNE fp32 -> bf16 bits
    unsigned u = __builtin_bit_cast(unsigned, f);
    unsigned r = (u + 0x7FFFu + ((u >> 16) & 1u)) >> 16;
    return (ushort_t)r;
}
__device__ inline float bf_lo(uint_t u) { return __builtin_bit_cast(float, u << 16); }
__device__ inline float bf_hi(uint_t u) { return __builtin_bit_cast(float, u & 0xFFFF0000u); }
__device__ inline uint_t pk2(float lo, float hi) {
    return (uint_t)f2bf(lo) | ((uint_t)f2bf(hi) << 16);
}

// [K][N] fp32 -> [N][K] bf16, one 32x32 tile per block (256 thr)
__device__ inline void transpose_tile(const float* __restrict__ in,
                                      ushort_t* __restrict__ out,
                                      int K, int N, int k0, int n0,
                                      ushort_t (*tile)[33]) {
    int tx = threadIdx.x & 31, ty = threadIdx.x >> 5;  // ty 0..7
    for (int r = ty; r < 32; r += 8)
        tile[r][tx] = f2bf(in[(size_t)(k0 + r) * N + n0 + tx]);
    __syncthreads();
    for (int r = ty; r < 32; r += 8)
        out[(size_t)(n0 + r) * K + k0 + tx] = tile[tx][r];
}

// Fused preprocessing: edge pass (deg count + ELL fill) | x->bf16 | W1^T | W2^T
__global__ __launch_bounds__(256) void prep_fused(
    const int* __restrict__ src, const int* __restrict__ dst,
    int* __restrict__ deg, int* __restrict__ col_ell,
    int* __restrict__ ovf_cnt, int* __restrict__ ovf, int e, int nb_e,
    const float* __restrict__ x, ushort_t* __restrict__ xb, long xcount, int nb_conv,
    const float* __restrict__ W1, ushort_t* __restrict__ w1t,
    const float* __restrict__ W2, ushort_t* __restrict__ w2t) {
    __shared__ ushort_t tile[32][33];
    int b = blockIdx.x;
    if (b < nb_e) {
        int i = b * 256 + threadIdx.x;
        if (i < e) {
            int s = src[i], d = dst[i];
            int slot = atomicAdd(&deg[d], 1);
            if (slot < MAXD) {
                col_ell[d * MAXD + slot] = s;
            } else {
                int k = atomicAdd(ovf_cnt, 1);
                ovf[2 * k] = d;
                ovf[2 * k + 1] = s;
            }
        }
        return;
    }
    b -= nb_e;
    if (b < nb_conv) {
        long i = ((long)b * 256 + threadIdx.x) * 4;
        if (i < xcount) {
            float4 v = *(const float4*)(x + i);
            ushort4 o = make_ushort4(f2bf(v.x), f2bf(v.y), f2bf(v.z), f2bf(v.w));
            *(ushort4*)(xb + i) = o;
        }
        return;
    }
    b -= nb_conv;
    if (b < 256) {  // W1: K=512, N=512 -> 16x16 tiles
        transpose_tile(W1, w1t, 512, 512, (b >> 4) * 32, (b & 15) * 32, tile);
        return;
    }
    b -= 256;       // W2: K=512, N=256 -> 8x16 tiles
    transpose_tile(W2, w2t, 512, 256, (b >> 3) * 32, (b & 7) * 32, tile);
}

// Layer-1 GEMM (+ dinv tail blocks).
// C[r][c] = bf16( sum_k A[r][k]*BT[c][k] )
// A:[M][K], BT:[N][K] bf16. 128x128 tile, BK=64, 4 waves, 4x4 16x16x32 frags.
// LDS swizzle: position s (16B chunks, 8/row) holds global granule s^(r&7).
__global__ __launch_bounds__(256) void gemm_mfma(
    const ushort_t* __restrict__ A, const ushort_t* __restrict__ BT,
    ushort_t* __restrict__ C,
    int M, int N, int K, int nbx, int gemm_blocks,
    const int* __restrict__ deg, float* __restrict__ dinv_out, int n) {
    __shared__ __align__(16) ushort_t As[8192];  // 128 rows x 64 k
    __shared__ __align__(16) ushort_t Bs[8192];

    if ((int)blockIdx.x >= gemm_blocks) {  // ---- dinv tail ----
        int i = ((int)blockIdx.x - gemm_blocks) * 256 + threadIdx.x;
        if (i < n) dinv_out[i] = 1.0f / sqrtf((float)(deg[i] + 1));
        return;
    }

    const int bx = (int)blockIdx.x % nbx, by = (int)blockIdx.x / nbx;
    const int tid = threadIdx.x;
    const int w = tid >> 6, lane = tid & 63;
    const int q = lane >> 4, ml = lane & 15;
    const int wm = (w >> 1) * 64, wn = (w & 1) * 64;
    const int row0 = by * 128, col0 = bx * 128;

    // staging: lane L covers row sub = L>>3, granule gsw = (L&7)^((L>>3)&7)
    const int rr = lane >> 3;                  // 0..7
    const int gsw = (lane & 7) ^ (rr & 7);     // global k-granule (x8 ushorts)
    const ushort_t* ga[4];
    const ushort_t* gb[4];
    ushort_t* la[4];
    ushort_t* lb[4];
#pragma unroll
    for (int rp = 0; rp < 4; rp++) {
        int r = rp * 32 + w * 8 + rr;
        int gra = min(row0 + r, M - 1);
        ga[rp] = A + (size_t)gra * K + gsw * 8;
        gb[rp] = BT + (size_t)(col0 + r) * K + gsw * 8;
        la[rp] = As + rp * 2048 + w * 512;  // wave-uniform; HW adds lane*16B
        lb[rp] = Bs + rp * 2048 + w * 512;
    }

    // fragment read offsets (ushort idx): row_loc*64 + ((g ^ (ml&7))*8)
    const int sel = ml & 7;
    int aoff[2][4], boff[2][4];
#pragma unroll
    for (int st = 0; st < 2; st++)
#pragma unroll
        for (int i = 0; i < 4; i++) {
            int g = q + st * 4;
            aoff[st][i] = (wm + i * 16 + ml) * 64 + ((g ^ sel) << 3);
            boff[st][i] = (wn + i * 16 + ml) * 64 + ((g ^ sel) << 3);
        }

    floatx4 acc[4][4];
#pragma unroll
    for (int i = 0; i < 4; i++)
#pragma unroll
        for (int j = 0; j < 4; j++) acc[i][j] = (floatx4)0.0f;

    for (int kt = 0; kt < K; kt += 64) {
#pragma unroll
        for (int rp = 0; rp < 4; rp++) {
            __builtin_amdgcn_global_load_lds(
                (const __attribute__((address_space(1))) unsigned*)ga[rp],
                (__attribute__((address_space(3))) unsigned*)la[rp], 16, 0, 0);
            __builtin_amdgcn_global_load_lds(
                (const __attribute__((address_space(1))) unsigned*)gb[rp],
                (__attribute__((address_space(3))) unsigned*)lb[rp], 16, 0, 0);
            ga[rp] += 64; gb[rp] += 64;
        }
        __syncthreads();
#pragma unroll
        for (int st = 0; st < 2; st++) {
            bf16x8 af[4], bfr[4];
#pragma unroll
            for (int i = 0; i < 4; i++) {
                af[i] = *(const bf16x8*)(As + aoff[st][i]);
                bfr[i] = *(const bf16x8*)(Bs + boff[st][i]);
            }
#pragma unroll
            for (int i = 0; i < 4; i++)
#pragma unroll
                for (int j = 0; j < 4; j++)
                    acc[i][j] = __builtin_amdgcn_mfma_f32_16x16x32_bf16(
                        af[i], bfr[j], acc[i][j], 0, 0, 0);
        }
        __syncthreads();
    }

    // epilogue: C/D layout col=lane&15, row=q*4+reg  [m89/m91]; store bf16
#pragma unroll
    for (int i = 0; i < 4; i++) {
        int rbase = row0 + wm + i * 16 + q * 4;
#pragma unroll
        for (int j = 0; j < 4; j++) {
            int gc = col0 + wn + j * 16 + ml;
#pragma unroll
            for (int r = 0; r < 4; r++) {
                int gr = rbase + r;
                if (gr < M) C[(size_t)gr * N + gc] = f2bf(acc[i][j][r]);
            }
        }
    }
}

// FUSED aggregate1 + layer-2 GEMM.
// A-operand rows are h1[r][k] = relu(pd_r*(pd_r*g[r][k] + sum ps*g[s][k]) + b1[k])
// computed on the fly per 64-wide K-slice from the unscaled layer-1 GEMM out g.
// Tile: BM=64 rows x BN=256 cols (single col-block -> gather happens once),
// BK=64, 256 thr / 4 waves (each wave: all 64 rows x 64 cols).
// Output g2[r][c] = bf16(dinv[r] * (h1 @ W2)[r][c])  (pre-scaled for agg2).
__global__ __launch_bounds__(256, 2) void gemm2_fused(
    const ushort_t* __restrict__ g,    // [n][512] bf16 (unscaled x@W1)
    const ushort_t* __restrict__ BT,   // w2t [256][512] bf16
    const int* __restrict__ deg, const int* __restrict__ col_ell,
    const int* __restrict__ ovf_cnt, const int* __restrict__ ovf,
    const float* __restrict__ dinv, const float* __restrict__ b1,
    ushort_t* __restrict__ g2, int M) {
    __shared__ __align__(16) ushort_t As[64 * 64];    //  8 KB
    __shared__ __align__(16) ushort_t Bs[256 * 64];   // 32 KB
    __shared__ int   cols_s[64][CAP];                 // 10 KB
    __shared__ float ps_s[64][CAP];                   // 10 KB
    __shared__ float b1_s[512];                       //  2 KB
    __shared__ short cnt_s[64];

    const int tid = threadIdx.x;
    const int w = tid >> 6, lane = tid & 63;
    const int q = lane >> 4, ml = lane & 15;
    const int wn = w * 64;
    const int row0 = (int)blockIdx.x * 64;

    // ---- prologue: bias + adjacency lists (self first, ps=0 pads -> self) ----
    for (int i = tid; i < 512; i += 256) b1_s[i] = b1[i];
    {
        int r = tid >> 2, jj = tid & 3;
        int rg = min(row0 + r, M - 1);
        int cnt = min(deg[rg], MAXD);
        float pd = dinv[rg];
        if (jj == 0) {
            cols_s[r][0] = rg;
            ps_s[r][0] = pd;
            cnt_s[r] = (short)(cnt + 1);
        }
        const int* cm = col_ell + (size_t)rg * MAXD;
        for (int j = jj; j < CAP - 1; j += 4) {
            bool vld = j < cnt;
            int c = vld ? cm[j] : rg;        // pad: self row (L1-hot), weight 0
            cols_s[r][j + 1] = c;
            ps_s[r][j + 1] = vld ? dinv[c] : 0.0f;
        }
    }
    const int nov = *ovf_cnt;  // ~always 0

    // ---- B staging (global_load_lds, same swizzle as gemm_mfma) ----
    const int rr = lane >> 3;
    const int gsw = (lane & 7) ^ (rr & 7);
    const ushort_t* gb[8];
    ushort_t* lb[8];
#pragma unroll
    for (int rp = 0; rp < 8; rp++) {
        gb[rp] = BT + (size_t)(rp * 32 + w * 8 + rr) * 512 + gsw * 8;
        lb[rp] = Bs + rp * 2048 + w * 512;
    }

    // fragment read offsets (wm = 0: all waves share the 64 A-rows)
    const int sel = ml & 7;
    int aoff[2][4], boff[2][4];
#pragma unroll
    for (int st = 0; st < 2; st++)
#pragma unroll
        for (int i = 0; i < 4; i++) {
            int gg = q + st * 4;
            aoff[st][i] = (i * 16 + ml) * 64 + ((gg ^ sel) << 3);
            boff[st][i] = (wn + i * 16 + ml) * 64 + ((gg ^ sel) << 3);
        }

    floatx4 acc[4][4];
#pragma unroll
    for (int i = 0; i < 4; i++)
#pragma unroll
        for (int j = 0; j < 4; j++) acc[i][j] = (floatx4)0.0f;

    // A staging geometry: 8 threads per row, 16B (8 bf16) per thread,
    // 2 passes of 32 rows. LDS pos = kg ^ (r&7) keeps the read-side swizzle.
    const int ar = tid >> 3;   // 0..31
    const int kg = tid & 7;    // k-granule

    __syncthreads();

    for (int kt = 0; kt < 512; kt += 64) {
#pragma unroll
        for (int rp = 0; rp < 8; rp++) {
            __builtin_amdgcn_global_load_lds(
                (const __attribute__((address_space(1))) unsigned*)gb[rp],
                (__attribute__((address_space(3))) unsigned*)lb[rp], 16, 0, 0);
            gb[rp] += 64;
        }

        const ushort_t* gk = g + kt + kg * 8;
#pragma unroll
        for (int p = 0; p < 2; p++) {
            const int r = ar + p * 32;
            const int cntR = (int)cnt_s[r];
            const float pdr = ps_s[r][0];
            float a[8];
#pragma unroll
            for (int k = 0; k < 8; k++) a[k] = 0.0f;
            for (int e0 = 0; e0 < cntR; e0 += 8) {
                uint4 u[8];
                float ps[8];
#pragma unroll
                for (int j = 0; j < 8; j++) {
                    int s = cols_s[r][e0 + j];
                    ps[j] = ps_s[r][e0 + j];
                    u[j] = *(const uint4*)(gk + (size_t)s * 512);
                }
#pragma unroll
                for (int j = 0; j < 8; j++) {
                    a[0] = fmaf(ps[j], bf_lo(u[j].x), a[0]);
                    a[1] = fmaf(ps[j], bf_hi(u[j].x), a[1]);
                    a[2] = fmaf(ps[j], bf_lo(u[j].y), a[2]);
                    a[3] = fmaf(ps[j], bf_hi(u[j].y), a[3]);
                    a[4] = fmaf(ps[j], bf_lo(u[j].z), a[4]);
                    a[5] = fmaf(ps[j], bf_hi(u[j].z), a[5]);
                    a[6] = fmaf(ps[j], bf_lo(u[j].w), a[6]);
                    a[7] = fmaf(ps[j], bf_hi(u[j].w), a[7]);
                }
            }
            for (int k2 = 0; k2 < nov; k2++) {  // ~never taken
                if (ovf[2 * k2] == cols_s[r][0]) {
                    int s = ovf[2 * k2 + 1];
                    float ps = dinv[s];
                    uint4 u = *(const uint4*)(gk + (size_t)s * 512);
                    a[0] = fmaf(ps, bf_lo(u.x), a[0]);
                    a[1] = fmaf(ps, bf_hi(u.x), a[1]);
                    a[2] = fmaf(ps, bf_lo(u.y), a[2]);
                    a[3] = fmaf(ps, bf_hi(u.y), a[3]);
                    a[4] = fmaf(ps, bf_lo(u.z), a[4]);
                    a[5] = fmaf(ps, bf_hi(u.z), a[5]);
                    a[6] = fmaf(ps, bf_lo(u.w), a[6]);
                    a[7] = fmaf(ps, bf_hi(u.w), a[7]);
                }
            }
            float4 bv0 = *(const float4*)(b1_s + kt + kg * 8);
            float4 bv1 = *(const float4*)(b1_s + kt + kg * 8 + 4);
            float h0 = fmaxf(fmaf(pdr, a[0], bv0.x), 0.0f);
            float h1 = fmaxf(fmaf(pdr, a[1], bv0.y), 0.0f);
            float h2 = fmaxf(fmaf(pdr, a[2], bv0.z), 0.0f);
            float h3 = fmaxf(fmaf(pdr, a[3], bv0.w), 0.0f);
            float h4 = fmaxf(fmaf(pdr, a[4], bv1.x), 0.0f);
            float h5 = fmaxf(fmaf(pdr, a[5], bv1.y), 0.0f);
            float h6 = fmaxf(fmaf(pdr, a[6], bv1.z), 0.0f);
            float h7 = fmaxf(fmaf(pdr, a[7], bv1.w), 0.0f);
            uint4 U;
            U.x = pk2(h0, h1);
            U.y = pk2(h2, h3);
            U.z = pk2(h4, h5);
            U.w = pk2(h6, h7);
            *(uint4*)(As + r * 64 + ((kg ^ (r & 7)) << 3)) = U;
        }
        __syncthreads();

#pragma unroll
        for (int st = 0; st < 2; st++) {
            bf16x8 af[4], bfr[4];
#pragma unroll
            for (int i = 0; i < 4; i++) {
                af[i] = *(const bf16x8*)(As + aoff[st][i]);
                bfr[i] = *(const bf16x8*)(Bs + boff[st][i]);
            }
#pragma unroll
            for (int i = 0; i < 4; i++)
#pragma unroll
                for (int j = 0; j < 4; j++)
                    acc[i][j] = __builtin_amdgcn_mfma_f32_16x16x32_bf16(
                        af[i], bfr[j], acc[i][j], 0, 0, 0);
        }
        __syncthreads();
    }

    // epilogue: g2 = bf16(dinv[row] * acc)  (pre-scaled for aggregate2)
#pragma unroll
    for (int i = 0; i < 4; i++) {
        int rbase = row0 + i * 16 + q * 4;
        float pd4[4];
#pragma unroll
        for (int r = 0; r < 4; r++)
            pd4[r] = (rbase + r < M) ? dinv[rbase + r] : 1.0f;
#pragma unroll
        for (int j = 0; j < 4; j++) {
            int gc = wn + j * 16 + ml;
#pragma unroll
            for (int r = 0; r < 4; r++) {
                int gr = rbase + r;
                if (gr < M) g2[(size_t)gr * 256 + gc] = f2bf(pd4[r] * acc[i][j][r]);
            }
        }
    }
}

// Layer-2 aggregate over PRE-SCALED g2: out = relu(pd*(g[d]+sum g[s]) + b)
// g: [n][256] bf16 as uint2; one wave per node; cols preloaded once.
__global__ __launch_bounds__(64) void aggregate2(const uint2* __restrict__ g,
                                                 const int* __restrict__ deg,
                                                 const int* __restrict__ col_ell,
                                                 const int* __restrict__ ovf_cnt,
                                                 const int* __restrict__ ovf,
                                                 const float* __restrict__ dinv,
                                                 const float* __restrict__ bias,
                                                 float* __restrict__ out) {
    const int d = blockIdx.x, t = threadIdx.x;
    const int cnt = min(deg[d], MAXD);
    const float pd = dinv[d];
    const size_t base = (size_t)d * 64 + t;
    const int* cm = col_ell + (size_t)d * MAXD;

    int cv = 0;
    float wv = 0.0f;
    if (t < MAXD && t < cnt) {
        cv = cm[t];
        wv = 1.0f;
    }
    float4 b = *(const float4*)(bias + t * 4);

    uint2 us = g[base];
    float a0 = bf_lo(us.x), a1 = bf_hi(us.x);
    float a2 = bf_lo(us.y), a3 = bf_hi(us.y);  // self term

    for (int e0 = 0; e0 < cnt; e0 += 8) {
        uint2 u[8];
        float ws[8];
#pragma unroll
        for (int j = 0; j < 8; j++) {
            int s = __shfl(cv, e0 + j);
            ws[j] = __shfl(wv, e0 + j);
            u[j] = g[(size_t)s * 64 + t];
        }
#pragma unroll
        for (int j = 0; j < 8; j++) {
            a0 = fmaf(ws[j], bf_lo(u[j].x), a0);
            a1 = fmaf(ws[j], bf_hi(u[j].x), a1);
            a2 = fmaf(ws[j], bf_lo(u[j].y), a2);
            a3 = fmaf(ws[j], bf_hi(u[j].y), a3);
        }
    }
    int nov = *ovf_cnt;  // ~always 0
    for (int k = 0; k < nov; k++) {
        if (ovf[2 * k] == d) {
            uint2 u = g[(size_t)ovf[2 * k + 1] * 64 + t];
            a0 += bf_lo(u.x); a1 += bf_hi(u.x);
            a2 += bf_lo(u.y); a3 += bf_hi(u.y);
        }
    }
    float4 o;
    o.x = fmaxf(fmaf(pd, a0, b.x), 0.0f);
    o.y = fmaxf(fmaf(pd, a1, b.y), 0.0f);
    o.z = fmaxf(fmaf(pd, a2, b.z), 0.0f);
    o.w = fmaxf(fmaf(pd, a3, b.w), 0.0f);
    *(float4*)(out + (size_t)d * 256 + t * 4) = o;
}

extern "C" void kernel_launch(void* const* d_in, const int* in_sizes, int n_in,
                              void* d_out, int out_size, void* d_ws, size_t ws_size,
                              hipStream_t stream) {
    const float* x  = (const float*)d_in[0];
    const int*   ei = (const int*)d_in[1];   // int32 on device
    const float* W1 = (const float*)d_in[2];
    const float* b1 = (const float*)d_in[3];
    const float* W2 = (const float*)d_in[4];
    const float* b2 = (const float*)d_in[5];
    float* out = (float*)d_out;

    const int FIN = 512, FH = 512, FOUT = 256;
    const int n = in_sizes[0] / FIN;  // 20000
    const int e = in_sizes[1] / 2;    // 160000
    const int* src = ei;
    const int* dst = ei + e;

    auto align_up = [](size_t v) { return (v + 255) & ~(size_t)255; };
    char* w = (char*)d_ws;
    int*      deg     = (int*)w;                 // deg[n] + ovf_cnt adjacent
    int*      ovf_cnt = deg + n;
    w += align_up((size_t)(n + 1) * 4);
    float*    dinv    = (float*)w;    w += align_up((size_t)n * 4);
    int*      col_ell = (int*)w;      w += align_up((size_t)n * MAXD * 4);
    int*      ovf     = (int*)w;      w += align_up((size_t)2048 * 4);
    ushort_t* xb      = (ushort_t*)w; w += align_up((size_t)n * FIN * 2);
    ushort_t* w1t     = (ushort_t*)w; w += align_up((size_t)FH * FIN * 2);
    ushort_t* w2t     = (ushort_t*)w; w += align_up((size_t)FOUT * FH * 2);
    ushort_t* g       = (ushort_t*)w; w += align_up((size_t)n * FH * 2);   // x@W1
    ushort_t* g2      = (ushort_t*)w; w += align_up((size_t)n * FH * 2);   // dinv*(h1@W2)

    const int nb_n = (n + 255) / 256;
    const int nb_e = (e + 255) / 256;
    const long xcount = (long)n * FIN;
    const int nb_conv = (int)((xcount / 4 + 255) / 256);

    hipMemsetAsync(deg, 0, (size_t)(n + 1) * 4, stream);  // deg + ovf_cnt

    prep_fused<<<nb_e + nb_conv + 256 + 128, 256, 0, stream>>>(
        src, dst, deg, col_ell, ovf_cnt, ovf, e, nb_e,
        x, xb, xcount, nb_conv, W1, w1t, W2, w2t);

    // layer 1 GEMM (unscaled) + dinv tail blocks
    {
        const int mb = (n + 127) / 128;
        int gemm_blocks = (FH / 128) * mb;
        gemm_mfma<<<gemm_blocks + nb_n, 256, 0, stream>>>(
            xb, w1t, g, n, FH, FIN, FH / 128, gemm_blocks, deg, dinv, n);
    }
    // fused aggregate1 + layer-2 GEMM (writes pre-scaled g2)
    gemm2_fused<<<(n + 63) / 64, 256, 0, stream>>>(
        g, w2t, deg, col_ell, ovf_cnt, ovf, dinv, b1, g2, n);

    aggregate2<<<n, 64, 0, stream>>>((const uint2*)g2, deg, col_ell, ovf_cnt,
                                     ovf, dinv, b2, out);

    (void)ws_size; (void)n_in; (void)out_size;
}

// Round 3
// 193.268 us; speedup vs baseline: 1.0296x; 1.0296x over previous
//
#include <hip/hip_runtime.h>

// ---------------------------------------------------------------------------
// 2-layer GCN forward (PyG GCNConv) on MI355X, round 9 = R7 revert.
//   out[d] = relu( p[d]*( sum_{s->d} p[s]*h[s] + p[d]*h[d] ) + b ),  h = x@W
// R8 post-mortem (measured): fusing aggregate1 into gemm2's A-staging
// collapsed the gather's parallelism from 20000 blocks to 313 (Occupancy
// 10%, MfmaUtil 3%, VALUBusy 19%, 1.1 TB/s) -> latency-bound, 63us vs the
// 33us serial pair it replaced. Fusion abandoned; this is the proven R7.
// Floor analysis: agg1/agg2 are L3-BW bound (~7 TB/s on 164/82 MB logical;
// uniform-random graph -> per-XCD reuse ~1.1x, XCD chunking can't help);
// prep is HBM-bound; harness fill+restores ~58 us of the timed window.
// ---------------------------------------------------------------------------

typedef __bf16 bf16x8 __attribute__((ext_vector_type(8)));
typedef float floatx4 __attribute__((ext_vector_type(4)));
typedef unsigned short ushort_t;
typedef unsigned int uint_t;

#define MAXD 32

__device__ inline ushort_t f2bf(float f) {  // RNE fp32 -> bf16 bits
    unsigned u = __builtin_bit_cast(unsigned, f);
    unsigned r = (u + 0x7FFFu + ((u >> 16) & 1u)) >> 16;
    return (ushort_t)r;
}
__device__ inline float bf_lo(uint_t u) { return __builtin_bit_cast(float, u << 16); }
__device__ inline float bf_hi(uint_t u) { return __builtin_bit_cast(float, u & 0xFFFF0000u); }

// [K][N] fp32 -> [N][K] bf16, one 32x32 tile per block (256 thr)
__device__ inline void transpose_tile(const float* __restrict__ in,
                                      ushort_t* __restrict__ out,
                                      int K, int N, int k0, int n0,
                                      ushort_t (*tile)[33]) {
    int tx = threadIdx.x & 31, ty = threadIdx.x >> 5;  // ty 0..7
    for (int r = ty; r < 32; r += 8)
        tile[r][tx] = f2bf(in[(size_t)(k0 + r) * N + n0 + tx]);
    __syncthreads();
    for (int r = ty; r < 32; r += 8)
        out[(size_t)(n0 + r) * K + k0 + tx] = tile[tx][r];
}

// Fused preprocessing: edge pass (deg count + ELL fill) | x->bf16 | W1^T | W2^T
__global__ __launch_bounds__(256) void prep_fused(
    const int* __restrict__ src, const int* __restrict__ dst,
    int* __restrict__ deg, int* __restrict__ col_ell,
    int* __restrict__ ovf_cnt, int* __restrict__ ovf, int e, int nb_e,
    const float* __restrict__ x, ushort_t* __restrict__ xb, long xcount, int nb_conv,
    const float* __restrict__ W1, ushort_t* __restrict__ w1t,
    const float* __restrict__ W2, ushort_t* __restrict__ w2t) {
    __shared__ ushort_t tile[32][33];
    int b = blockIdx.x;
    if (b < nb_e) {
        int i = b * 256 + threadIdx.x;
        if (i < e) {
            int s = src[i], d = dst[i];
            int slot = atomicAdd(&deg[d], 1);
            if (slot < MAXD) {
                col_ell[d * MAXD + slot] = s;
            } else {
                int k = atomicAdd(ovf_cnt, 1);
                ovf[2 * k] = d;
                ovf[2 * k + 1] = s;
            }
        }
        return;
    }
    b -= nb_e;
    if (b < nb_conv) {
        long i = ((long)b * 256 + threadIdx.x) * 4;
        if (i < xcount) {
            float4 v = *(const float4*)(x + i);
            ushort4 o = make_ushort4(f2bf(v.x), f2bf(v.y), f2bf(v.z), f2bf(v.w));
            *(ushort4*)(xb + i) = o;
        }
        return;
    }
    b -= nb_conv;
    if (b < 256) {  // W1: K=512, N=512 -> 16x16 tiles
        transpose_tile(W1, w1t, 512, 512, (b >> 4) * 32, (b & 15) * 32, tile);
        return;
    }
    b -= 256;       // W2: K=512, N=256 -> 8x16 tiles
    transpose_tile(W2, w2t, 512, 256, (b >> 3) * 32, (b & 7) * 32, tile);
}

// GEMM (+ optional dinv tail blocks).
// C[r][c] = bf16( (scale?dinv[r]:1) * sum_k A[r][k]*BT[c][k] )
// A:[M][K], BT:[N][K] bf16. 128x128 tile, BK=64, 4 waves, 4x4 16x16x32 frags.
// LDS swizzle: position s (16B chunks, 8/row) holds global granule s^(r&7).
__global__ __launch_bounds__(256) void gemm_mfma(
    const ushort_t* __restrict__ A, const ushort_t* __restrict__ BT,
    const float* __restrict__ dinv, ushort_t* __restrict__ C,
    int M, int N, int K, int nbx, int gemm_blocks, int scale,
    const int* __restrict__ deg, float* __restrict__ dinv_out, int n) {
    __shared__ __align__(16) ushort_t As[8192];  // 128 rows x 64 k
    __shared__ __align__(16) ushort_t Bs[8192];

    if ((int)blockIdx.x >= gemm_blocks) {  // ---- dinv tail ----
        int i = ((int)blockIdx.x - gemm_blocks) * 256 + threadIdx.x;
        if (i < n) dinv_out[i] = 1.0f / sqrtf((float)(deg[i] + 1));
        return;
    }

    const int bx = (int)blockIdx.x % nbx, by = (int)blockIdx.x / nbx;
    const int tid = threadIdx.x;
    const int w = tid >> 6, lane = tid & 63;
    const int q = lane >> 4, ml = lane & 15;
    const int wm = (w >> 1) * 64, wn = (w & 1) * 64;
    const int row0 = by * 128, col0 = bx * 128;

    // staging: lane L covers row sub = L>>3, granule gsw = (L&7)^((L>>3)&7)
    const int rr = lane >> 3;                  // 0..7
    const int gsw = (lane & 7) ^ (rr & 7);     // global k-granule (x8 ushorts)
    const ushort_t* ga[4];
    const ushort_t* gb[4];
    ushort_t* la[4];
    ushort_t* lb[4];
#pragma unroll
    for (int rp = 0; rp < 4; rp++) {
        int r = rp * 32 + w * 8 + rr;
        int gra = min(row0 + r, M - 1);
        ga[rp] = A + (size_t)gra * K + gsw * 8;
        gb[rp] = BT + (size_t)(col0 + r) * K + gsw * 8;
        la[rp] = As + rp * 2048 + w * 512;  // wave-uniform; HW adds lane*16B
        lb[rp] = Bs + rp * 2048 + w * 512;
    }

    // fragment read offsets (ushort idx): row_loc*64 + ((g ^ (ml&7))*8)
    const int sel = ml & 7;
    int aoff[2][4], boff[2][4];
#pragma unroll
    for (int st = 0; st < 2; st++)
#pragma unroll
        for (int i = 0; i < 4; i++) {
            int g = q + st * 4;
            aoff[st][i] = (wm + i * 16 + ml) * 64 + ((g ^ sel) << 3);
            boff[st][i] = (wn + i * 16 + ml) * 64 + ((g ^ sel) << 3);
        }

    floatx4 acc[4][4];
#pragma unroll
    for (int i = 0; i < 4; i++)
#pragma unroll
        for (int j = 0; j < 4; j++) acc[i][j] = (floatx4)0.0f;

    for (int kt = 0; kt < K; kt += 64) {
#pragma unroll
        for (int rp = 0; rp < 4; rp++) {
            __builtin_amdgcn_global_load_lds(
                (const __attribute__((address_space(1))) unsigned*)ga[rp],
                (__attribute__((address_space(3))) unsigned*)la[rp], 16, 0, 0);
            __builtin_amdgcn_global_load_lds(
                (const __attribute__((address_space(1))) unsigned*)gb[rp],
                (__attribute__((address_space(3))) unsigned*)lb[rp], 16, 0, 0);
            ga[rp] += 64; gb[rp] += 64;
        }
        __syncthreads();
#pragma unroll
        for (int st = 0; st < 2; st++) {
            bf16x8 af[4], bfr[4];
#pragma unroll
            for (int i = 0; i < 4; i++) {
                af[i] = *(const bf16x8*)(As + aoff[st][i]);
                bfr[i] = *(const bf16x8*)(Bs + boff[st][i]);
            }
#pragma unroll
            for (int i = 0; i < 4; i++)
#pragma unroll
                for (int j = 0; j < 4; j++)
                    acc[i][j] = __builtin_amdgcn_mfma_f32_16x16x32_bf16(
                        af[i], bfr[j], acc[i][j], 0, 0, 0);
        }
        __syncthreads();
    }

    // epilogue: C/D layout col=lane&15, row=q*4+reg  [m89/m91]; store bf16
#pragma unroll
    for (int i = 0; i < 4; i++) {
        int rbase = row0 + wm + i * 16 + q * 4;
        float pd[4];
#pragma unroll
        for (int r = 0; r < 4; r++)
            pd[r] = (scale && rbase + r < M) ? dinv[rbase + r] : 1.0f;
#pragma unroll
        for (int j = 0; j < 4; j++) {
            int gc = col0 + wn + j * 16 + ml;
#pragma unroll
            for (int r = 0; r < 4; r++) {
                int gr = rbase + r;
                if (gr < M) C[(size_t)gr * N + gc] = f2bf(pd[r] * acc[i][j][r]);
            }
        }
    }
}

// Layer-1 aggregate over UNSCALED g: h1 = relu(pd*(pd*g[d] + sum ps*g[s]) + b)
// g: [n][512] bf16 as uint2; 128 thr/block. All <=32 cols + dinv preloaded
// into lanes 0-31 of each wave; batches are pure shfl + row-gather.
__global__ __launch_bounds__(128) void aggregate1(const uint2* __restrict__ g,
                                                  const int* __restrict__ deg,
                                                  const int* __restrict__ col_ell,
                                                  const int* __restrict__ ovf_cnt,
                                                  const int* __restrict__ ovf,
                                                  const float* __restrict__ dinv,
                                                  const float* __restrict__ bias,
                                                  uint2* __restrict__ out) {
    const int d = blockIdx.x, t = threadIdx.x;
    const int cnt = min(deg[d], MAXD);
    const float pd = dinv[d];
    const size_t base = (size_t)d * 128 + t;
    const int* cm = col_ell + (size_t)d * MAXD;

    // preload ALL cols + dinv once (lanes 0..31 of each wave; pads -> 0)
    const int lane = t & 63;
    int cv = 0;
    float dv = 0.0f;
    if (lane < MAXD && lane < cnt) {
        cv = cm[lane];
        dv = dinv[cv];
    }
    float4 b = *(const float4*)(bias + t * 4);

    uint2 us = g[base];
    float a0 = pd * bf_lo(us.x), a1 = pd * bf_hi(us.x);
    float a2 = pd * bf_lo(us.y), a3 = pd * bf_hi(us.y);  // self (pd*g[d])

    for (int e0 = 0; e0 < cnt; e0 += 8) {
        uint2 u[8];
        float ps[8];
#pragma unroll
        for (int j = 0; j < 8; j++) {
            int s = __shfl(cv, e0 + j);
            ps[j] = __shfl(dv, e0 + j);
            u[j] = g[(size_t)s * 128 + t];
        }
#pragma unroll
        for (int j = 0; j < 8; j++) {
            a0 = fmaf(ps[j], bf_lo(u[j].x), a0);
            a1 = fmaf(ps[j], bf_hi(u[j].x), a1);
            a2 = fmaf(ps[j], bf_lo(u[j].y), a2);
            a3 = fmaf(ps[j], bf_hi(u[j].y), a3);
        }
    }
    int nov = *ovf_cnt;  // ~always 0
    for (int k = 0; k < nov; k++) {
        if (ovf[2 * k] == d) {
            int s = ovf[2 * k + 1];
            float ps = dinv[s];
            uint2 u = g[(size_t)s * 128 + t];
            a0 = fmaf(ps, bf_lo(u.x), a0);
            a1 = fmaf(ps, bf_hi(u.x), a1);
            a2 = fmaf(ps, bf_lo(u.y), a2);
            a3 = fmaf(ps, bf_hi(u.y), a3);
        }
    }
    float o0 = fmaxf(fmaf(pd, a0, b.x), 0.0f);
    float o1 = fmaxf(fmaf(pd, a1, b.y), 0.0f);
    float o2 = fmaxf(fmaf(pd, a2, b.z), 0.0f);
    float o3 = fmaxf(fmaf(pd, a3, b.w), 0.0f);
    uint2 o;
    o.x = (uint_t)f2bf(o0) | ((uint_t)f2bf(o1) << 16);
    o.y = (uint_t)f2bf(o2) | ((uint_t)f2bf(o3) << 16);
    out[base] = o;
}

// Layer-2 aggregate over PRE-SCALED g2: out = relu(pd*(g[d]+sum g[s]) + b)
// g: [n][256] bf16 as uint2; one wave per node; cols preloaded once.
__global__ __launch_bounds__(64) void aggregate2(const uint2* __restrict__ g,
                                                 const int* __restrict__ deg,
                                                 const int* __restrict__ col_ell,
                                                 const int* __restrict__ ovf_cnt,
                                                 const int* __restrict__ ovf,
                                                 const float* __restrict__ dinv,
                                                 const float* __restrict__ bias,
                                                 float* __restrict__ out) {
    const int d = blockIdx.x, t = threadIdx.x;
    const int cnt = min(deg[d], MAXD);
    const float pd = dinv[d];
    const size_t base = (size_t)d * 64 + t;
    const int* cm = col_ell + (size_t)d * MAXD;

    int cv = 0;
    float wv = 0.0f;
    if (t < MAXD && t < cnt) {
        cv = cm[t];
        wv = 1.0f;
    }
    float4 b = *(const float4*)(bias + t * 4);

    uint2 us = g[base];
    float a0 = bf_lo(us.x), a1 = bf_hi(us.x);
    float a2 = bf_lo(us.y), a3 = bf_hi(us.y);  // self term

    for (int e0 = 0; e0 < cnt; e0 += 8) {
        uint2 u[8];
        float ws[8];
#pragma unroll
        for (int j = 0; j < 8; j++) {
            int s = __shfl(cv, e0 + j);
            ws[j] = __shfl(wv, e0 + j);
            u[j] = g[(size_t)s * 64 + t];
        }
#pragma unroll
        for (int j = 0; j < 8; j++) {
            a0 = fmaf(ws[j], bf_lo(u[j].x), a0);
            a1 = fmaf(ws[j], bf_hi(u[j].x), a1);
            a2 = fmaf(ws[j], bf_lo(u[j].y), a2);
            a3 = fmaf(ws[j], bf_hi(u[j].y), a3);
        }
    }
    int nov = *ovf_cnt;  // ~always 0
    for (int k = 0; k < nov; k++) {
        if (ovf[2 * k] == d) {
            uint2 u = g[(size_t)ovf[2 * k + 1] * 64 + t];
            a0 += bf_lo(u.x); a1 += bf_hi(u.x);
            a2 += bf_lo(u.y); a3 += bf_hi(u.y);
        }
    }
    float4 o;
    o.x = fmaxf(fmaf(pd, a0, b.x), 0.0f);
    o.y = fmaxf(fmaf(pd, a1, b.y), 0.0f);
    o.z = fmaxf(fmaf(pd, a2, b.z), 0.0f);
    o.w = fmaxf(fmaf(pd, a3, b.w), 0.0f);
    *(float4*)(out + (size_t)d * 256 + t * 4) = o;
}

extern "C" void kernel_launch(void* const* d_in, const int* in_sizes, int n_in,
                              void* d_out, int out_size, void* d_ws, size_t ws_size,
                              hipStream_t stream) {
    const float* x  = (const float*)d_in[0];
    const int*   ei = (const int*)d_in[1];   // int32 on device
    const float* W1 = (const float*)d_in[2];
    const float* b1 = (const float*)d_in[3];
    const float* W2 = (const float*)d_in[4];
    const float* b2 = (const float*)d_in[5];
    float* out = (float*)d_out;

    const int FIN = 512, FH = 512, FOUT = 256;
    const int n = in_sizes[0] / FIN;  // 20000
    const int e = in_sizes[1] / 2;    // 160000
    const int* src = ei;
    const int* dst = ei + e;

    auto align_up = [](size_t v) { return (v + 255) & ~(size_t)255; };
    char* w = (char*)d_ws;
    int*      deg     = (int*)w;                 // deg[n] + ovf_cnt adjacent
    int*      ovf_cnt = deg + n;
    w += align_up((size_t)(n + 1) * 4);
    float*    dinv    = (float*)w;    w += align_up((size_t)n * 4);
    int*      col_ell = (int*)w;      w += align_up((size_t)n * MAXD * 4);
    int*      ovf     = (int*)w;      w += align_up((size_t)2048 * 4);
    ushort_t* xb      = (ushort_t*)w; w += align_up((size_t)n * FIN * 2);
    ushort_t* w1t     = (ushort_t*)w; w += align_up((size_t)FH * FIN * 2);
    ushort_t* w2t     = (ushort_t*)w; w += align_up((size_t)FOUT * FH * 2);
    ushort_t* g       = (ushort_t*)w; w += align_up((size_t)n * FH * 2);  // reused L2
    ushort_t* h1b     = (ushort_t*)w; w += align_up((size_t)n * FH * 2);

    const int nb_n = (n + 255) / 256;
    const int nb_e = (e + 255) / 256;
    const long xcount = (long)n * FIN;
    const int nb_conv = (int)((xcount / 4 + 255) / 256);

    hipMemsetAsync(deg, 0, (size_t)(n + 1) * 4, stream);  // deg + ovf_cnt

    prep_fused<<<nb_e + nb_conv + 256 + 128, 256, 0, stream>>>(
        src, dst, deg, col_ell, ovf_cnt, ovf, e, nb_e,
        x, xb, xcount, nb_conv, W1, w1t, W2, w2t);

    const int mb = (n + 127) / 128;
    // layer 1 GEMM (unscaled) + dinv tail blocks
    {
        int gemm_blocks = (FH / 128) * mb;
        gemm_mfma<<<gemm_blocks + nb_n, 256, 0, stream>>>(
            xb, w1t, nullptr, g, n, FH, FIN, FH / 128, gemm_blocks, 0,
            deg, dinv, n);
    }
    aggregate1<<<n, 128, 0, stream>>>((const uint2*)g, deg, col_ell, ovf_cnt,
                                      ovf, dinv, b1, (uint2*)h1b);
    // layer 2 GEMM (scaled by dinv in epilogue)
    {
        int gemm_blocks = (FOUT / 128) * mb;
        gemm_mfma<<<gemm_blocks, 256, 0, stream>>>(
            h1b, w2t, dinv, g, n, FOUT, FH, FOUT / 128, gemm_blocks, 1,
            nullptr, nullptr, 0);
    }
    aggregate2<<<n, 64, 0, stream>>>((const uint2*)g, deg, col_ell, ovf_cnt,
                                     ovf, dinv, b2, out);

    (void)ws_size; (void)n_in; (void)out_size;
}

// Round 4
// 190.624 us; speedup vs baseline: 1.0439x; 1.0139x over previous
//
#include <hip/hip_runtime.h>

// ---------------------------------------------------------------------------
// 2-layer GCN forward (PyG GCNConv) on MI355X, round 10.
//   out[d] = relu( p[d]*( sum_{s->d} p[s]*h[s] + p[d]*h[d] ) + b ),  h = x@W
// R10: retry agg1+gemm2 fusion with the R8 occupancy lesson applied.
//  - R8 (BM=64, 313 blocks): 1.2 blocks/CU, 5 waves/CU -> latency-bound 63us.
//  - R10 (BM=16, 1250 blocks, 41KB LDS): 3 blocks/CU, 12 waves/CU, 16 thr/row,
//    4x smaller per-block gather. Numerics identical to R8 (which PASSED).
//  - eliminates h1b round-trip (61MB L3) + one launch; overlaps the 180MB
//    gather with W2 MFMAs. 5 dispatches.
// Floor analysis: agg gather is L3-BW bound (~7 TB/s, uniform-random graph,
// per-XCD reuse ~1.1x); prep is HBM-bound; harness fill+restores ~58us.
// ---------------------------------------------------------------------------

typedef __bf16 bf16x8 __attribute__((ext_vector_type(8)));
typedef float floatx4 __attribute__((ext_vector_type(4)));
typedef unsigned short ushort_t;
typedef unsigned int uint_t;

#define MAXD 32
#define CAP 40  // self + 32 ELL + pad (pads: ps=0, col=self -> L1-hot)

__device__ inline ushort_t f2bf(float f) {  // RNE fp32 -> bf16 bits
    unsigned u = __builtin_bit_cast(unsigned, f);
    unsigned r = (u + 0x7FFFu + ((u >> 16) & 1u)) >> 16;
    return (ushort_t)r;
}
__device__ inline float bf_lo(uint_t u) { return __builtin_bit_cast(float, u << 16); }
__device__ inline float bf_hi(uint_t u) { return __builtin_bit_cast(float, u & 0xFFFF0000u); }
__device__ inline uint_t pk2(float lo, float hi) {
    return (uint_t)f2bf(lo) | ((uint_t)f2bf(hi) << 16);
}

// [K][N] fp32 -> [N][K] bf16, one 32x32 tile per block (256 thr)
__device__ inline void transpose_tile(const float* __restrict__ in,
                                      ushort_t* __restrict__ out,
                                      int K, int N, int k0, int n0,
                                      ushort_t (*tile)[33]) {
    int tx = threadIdx.x & 31, ty = threadIdx.x >> 5;  // ty 0..7
    for (int r = ty; r < 32; r += 8)
        tile[r][tx] = f2bf(in[(size_t)(k0 + r) * N + n0 + tx]);
    __syncthreads();
    for (int r = ty; r < 32; r += 8)
        out[(size_t)(n0 + r) * K + k0 + tx] = tile[tx][r];
}

// Fused preprocessing: edge pass (deg count + ELL fill) | x->bf16 | W1^T | W2^T
__global__ __launch_bounds__(256) void prep_fused(
    const int* __restrict__ src, const int* __restrict__ dst,
    int* __restrict__ deg, int* __restrict__ col_ell,
    int* __restrict__ ovf_cnt, int* __restrict__ ovf, int e, int nb_e,
    const float* __restrict__ x, ushort_t* __restrict__ xb, long xcount, int nb_conv,
    const float* __restrict__ W1, ushort_t* __restrict__ w1t,
    const float* __restrict__ W2, ushort_t* __restrict__ w2t) {
    __shared__ ushort_t tile[32][33];
    int b = blockIdx.x;
    if (b < nb_e) {
        int i = b * 256 + threadIdx.x;
        if (i < e) {
            int s = src[i], d = dst[i];
            int slot = atomicAdd(&deg[d], 1);
            if (slot < MAXD) {
                col_ell[d * MAXD + slot] = s;
            } else {
                int k = atomicAdd(ovf_cnt, 1);
                ovf[2 * k] = d;
                ovf[2 * k + 1] = s;
            }
        }
        return;
    }
    b -= nb_e;
    if (b < nb_conv) {
        long i = ((long)b * 256 + threadIdx.x) * 4;
        if (i < xcount) {
            float4 v = *(const float4*)(x + i);
            ushort4 o = make_ushort4(f2bf(v.x), f2bf(v.y), f2bf(v.z), f2bf(v.w));
            *(ushort4*)(xb + i) = o;
        }
        return;
    }
    b -= nb_conv;
    if (b < 256) {  // W1: K=512, N=512 -> 16x16 tiles
        transpose_tile(W1, w1t, 512, 512, (b >> 4) * 32, (b & 15) * 32, tile);
        return;
    }
    b -= 256;       // W2: K=512, N=256 -> 8x16 tiles
    transpose_tile(W2, w2t, 512, 256, (b >> 3) * 32, (b & 7) * 32, tile);
}

// Layer-1 GEMM (+ dinv tail blocks).
// C[r][c] = bf16( sum_k A[r][k]*BT[c][k] ),  A:[M][K], BT:[N][K] bf16.
// 128x128 tile, BK=64, 4 waves, 4x4 16x16x32 frags.
// LDS swizzle: position s (16B chunks, 8/row) holds global granule s^(r&7).
__global__ __launch_bounds__(256) void gemm_mfma(
    const ushort_t* __restrict__ A, const ushort_t* __restrict__ BT,
    ushort_t* __restrict__ C,
    int M, int N, int K, int nbx, int gemm_blocks,
    const int* __restrict__ deg, float* __restrict__ dinv_out, int n) {
    __shared__ __align__(16) ushort_t As[8192];  // 128 rows x 64 k
    __shared__ __align__(16) ushort_t Bs[8192];

    if ((int)blockIdx.x >= gemm_blocks) {  // ---- dinv tail ----
        int i = ((int)blockIdx.x - gemm_blocks) * 256 + threadIdx.x;
        if (i < n) dinv_out[i] = 1.0f / sqrtf((float)(deg[i] + 1));
        return;
    }

    const int bx = (int)blockIdx.x % nbx, by = (int)blockIdx.x / nbx;
    const int tid = threadIdx.x;
    const int w = tid >> 6, lane = tid & 63;
    const int q = lane >> 4, ml = lane & 15;
    const int wm = (w >> 1) * 64, wn = (w & 1) * 64;
    const int row0 = by * 128, col0 = bx * 128;

    // staging: lane L covers row sub = L>>3, granule gsw = (L&7)^((L>>3)&7)
    const int rr = lane >> 3;                  // 0..7
    const int gsw = (lane & 7) ^ (rr & 7);     // global k-granule (x8 ushorts)
    const ushort_t* ga[4];
    const ushort_t* gb[4];
    ushort_t* la[4];
    ushort_t* lb[4];
#pragma unroll
    for (int rp = 0; rp < 4; rp++) {
        int r = rp * 32 + w * 8 + rr;
        int gra = min(row0 + r, M - 1);
        ga[rp] = A + (size_t)gra * K + gsw * 8;
        gb[rp] = BT + (size_t)(col0 + r) * K + gsw * 8;
        la[rp] = As + rp * 2048 + w * 512;  // wave-uniform; HW adds lane*16B
        lb[rp] = Bs + rp * 2048 + w * 512;
    }

    // fragment read offsets (ushort idx): row_loc*64 + ((g ^ (ml&7))*8)
    const int sel = ml & 7;
    int aoff[2][4], boff[2][4];
#pragma unroll
    for (int st = 0; st < 2; st++)
#pragma unroll
        for (int i = 0; i < 4; i++) {
            int g = q + st * 4;
            aoff[st][i] = (wm + i * 16 + ml) * 64 + ((g ^ sel) << 3);
            boff[st][i] = (wn + i * 16 + ml) * 64 + ((g ^ sel) << 3);
        }

    floatx4 acc[4][4];
#pragma unroll
    for (int i = 0; i < 4; i++)
#pragma unroll
        for (int j = 0; j < 4; j++) acc[i][j] = (floatx4)0.0f;

    for (int kt = 0; kt < K; kt += 64) {
#pragma unroll
        for (int rp = 0; rp < 4; rp++) {
            __builtin_amdgcn_global_load_lds(
                (const __attribute__((address_space(1))) unsigned*)ga[rp],
                (__attribute__((address_space(3))) unsigned*)la[rp], 16, 0, 0);
            __builtin_amdgcn_global_load_lds(
                (const __attribute__((address_space(1))) unsigned*)gb[rp],
                (__attribute__((address_space(3))) unsigned*)lb[rp], 16, 0, 0);
            ga[rp] += 64; gb[rp] += 64;
        }
        __syncthreads();
#pragma unroll
        for (int st = 0; st < 2; st++) {
            bf16x8 af[4], bfr[4];
#pragma unroll
            for (int i = 0; i < 4; i++) {
                af[i] = *(const bf16x8*)(As + aoff[st][i]);
                bfr[i] = *(const bf16x8*)(Bs + boff[st][i]);
            }
#pragma unroll
            for (int i = 0; i < 4; i++)
#pragma unroll
                for (int j = 0; j < 4; j++)
                    acc[i][j] = __builtin_amdgcn_mfma_f32_16x16x32_bf16(
                        af[i], bfr[j], acc[i][j], 0, 0, 0);
        }
        __syncthreads();
    }

    // epilogue: C/D layout col=lane&15, row=q*4+reg  [m89/m91]; store bf16
#pragma unroll
    for (int i = 0; i < 4; i++) {
        int rbase = row0 + wm + i * 16 + q * 4;
#pragma unroll
        for (int j = 0; j < 4; j++) {
            int gc = col0 + wn + j * 16 + ml;
#pragma unroll
            for (int r = 0; r < 4; r++) {
                int gr = rbase + r;
                if (gr < M) C[(size_t)gr * N + gc] = f2bf(acc[i][j][r]);
            }
        }
    }
}

// FUSED aggregate1 + layer-2 GEMM, BM=16 (R8 numerics, R10 tiling).
// h1[r][k] = relu(pd_r*(pd_r*g[r][k] + sum ps*g[s][k]) + b1[k]) computed
// per 64-wide K-slice as the A-operand; B = w2t (all 256 cols).
// 1250 blocks x 256 thr (4 waves); each wave: rows 0..15 x cols w*64..w*64+63.
// g2[r][c] = bf16(dinv[r] * (h1 @ W2)[r][c])  (pre-scaled for agg2).
__global__ __launch_bounds__(256) void agg1gemm2(
    const ushort_t* __restrict__ g,    // [n][512] bf16 (unscaled x@W1)
    const ushort_t* __restrict__ BT,   // w2t [256][512] bf16
    const int* __restrict__ deg, const int* __restrict__ col_ell,
    const int* __restrict__ ovf_cnt, const int* __restrict__ ovf,
    const float* __restrict__ dinv, const float* __restrict__ b1,
    ushort_t* __restrict__ g2, int M) {
    __shared__ __align__(16) ushort_t As[16 * 64];    //  2 KB
    __shared__ __align__(16) ushort_t Bs[256 * 64];   // 32 KB
    __shared__ int2  adj_s[16][CAP];                  //  5 KB (.x=col,.y=ps bits)
    __shared__ float b1_s[512];                       //  2 KB
    __shared__ int   cnt_s[16];

    const int tid = threadIdx.x;
    const int w = tid >> 6, lane = tid & 63;
    const int q = lane >> 4, ml = lane & 15;
    const int wn = w * 64;
    const int row0 = (int)blockIdx.x * 16;

    // ---- prologue: bias + adjacency (slot0=self/pd; pads col=self, ps=0) ----
    for (int i = tid; i < 512; i += 256) b1_s[i] = b1[i];
    {
        int r = tid >> 4, jj = tid & 15;   // 16 threads per row
        int rg = min(row0 + r, M - 1);
        int cnt = min(deg[rg], MAXD);
        const int* cm = col_ell + (size_t)rg * MAXD;
#pragma unroll
        for (int pass = 0; pass < 3; pass++) {
            int j = jj + pass * 16;
            if (j >= CAP) break;
            int2 a;
            if (j == 0) {
                a.x = rg;
                a.y = __builtin_bit_cast(int, dinv[rg]);
                cnt_s[r] = cnt + 1;
            } else {
                bool vld = (j - 1) < cnt;
                int c = vld ? cm[j - 1] : rg;   // pad: self row (hot), weight 0
                a.x = c;
                a.y = vld ? __builtin_bit_cast(int, dinv[c]) : 0;
            }
            adj_s[r][j] = a;
        }
    }
    const int nov = *ovf_cnt;  // ~always 0

    // ---- B staging (global_load_lds, same swizzle as gemm_mfma) ----
    const int rr = lane >> 3;
    const int gsw = (lane & 7) ^ (rr & 7);
    const ushort_t* gb[8];
    ushort_t* lb[8];
#pragma unroll
    for (int rp = 0; rp < 8; rp++) {
        gb[rp] = BT + (size_t)(rp * 32 + w * 8 + rr) * 512 + gsw * 8;
        lb[rp] = Bs + rp * 2048 + w * 512;
    }

    // fragment read offsets (A has 16 rows -> single M-frag)
    const int sel = ml & 7;
    int aoff[2], boff[2][4];
#pragma unroll
    for (int st = 0; st < 2; st++) {
        int gg = q + st * 4;
        aoff[st] = ml * 64 + ((gg ^ sel) << 3);
#pragma unroll
        for (int i = 0; i < 4; i++)
            boff[st][i] = (wn + i * 16 + ml) * 64 + ((gg ^ sel) << 3);
    }

    floatx4 acc[4];
#pragma unroll
    for (int j = 0; j < 4; j++) acc[j] = (floatx4)0.0f;

    // gather geometry: 16 threads/row, uint2 (4 feats) each
    const int gr_ = tid >> 4;   // row 0..15
    const int fc = tid & 15;    // feat chunk (4 feats)

    __syncthreads();
    const int cntR = cnt_s[gr_];
    const float pdr = __builtin_bit_cast(float, adj_s[gr_][0].y);
    const int selfR = adj_s[gr_][0].x;

    for (int kt = 0; kt < 512; kt += 64) {
#pragma unroll
        for (int rp = 0; rp < 8; rp++) {
            __builtin_amdgcn_global_load_lds(
                (const __attribute__((address_space(1))) unsigned*)gb[rp],
                (__attribute__((address_space(3))) unsigned*)lb[rp], 16, 0, 0);
            gb[rp] += 64;
        }

        const ushort_t* gk = g + kt + fc * 4;
        float a0 = 0.0f, a1 = 0.0f, a2 = 0.0f, a3 = 0.0f;
        for (int e0 = 0; e0 < cntR; e0 += 8) {
            uint2 u[8];
            float ps[8];
#pragma unroll
            for (int j = 0; j < 8; j++) {
                int2 cp = adj_s[gr_][e0 + j];
                ps[j] = __builtin_bit_cast(float, cp.y);
                u[j] = *(const uint2*)(gk + (size_t)cp.x * 512);
            }
#pragma unroll
            for (int j = 0; j < 8; j++) {
                a0 = fmaf(ps[j], bf_lo(u[j].x), a0);
                a1 = fmaf(ps[j], bf_hi(u[j].x), a1);
                a2 = fmaf(ps[j], bf_lo(u[j].y), a2);
                a3 = fmaf(ps[j], bf_hi(u[j].y), a3);
            }
        }
        for (int k2 = 0; k2 < nov; k2++) {  // ~never taken
            if (ovf[2 * k2] == selfR) {
                int s = ovf[2 * k2 + 1];
                float ps = dinv[s];
                uint2 u = *(const uint2*)(gk + (size_t)s * 512);
                a0 = fmaf(ps, bf_lo(u.x), a0);
                a1 = fmaf(ps, bf_hi(u.x), a1);
                a2 = fmaf(ps, bf_lo(u.y), a2);
                a3 = fmaf(ps, bf_hi(u.y), a3);
            }
        }
        float4 bv = *(const float4*)(b1_s + kt + fc * 4);
        float h0 = fmaxf(fmaf(pdr, a0, bv.x), 0.0f);
        float h1 = fmaxf(fmaf(pdr, a1, bv.y), 0.0f);
        float h2 = fmaxf(fmaf(pdr, a2, bv.z), 0.0f);
        float h3 = fmaxf(fmaf(pdr, a3, bv.w), 0.0f);
        uint2 U;
        U.x = pk2(h0, h1);
        U.y = pk2(h2, h3);
        // As swizzle: granule gran=fc>>1 goes to position gran^(row&7)
        *(uint2*)(As + gr_ * 64 + (((fc >> 1) ^ (gr_ & 7)) << 3) + (fc & 1) * 4) = U;

        __syncthreads();  // drains vmcnt (B in LDS) + As visible

#pragma unroll
        for (int st = 0; st < 2; st++) {
            bf16x8 af = *(const bf16x8*)(As + aoff[st]);
#pragma unroll
            for (int j = 0; j < 4; j++) {
                bf16x8 bfr = *(const bf16x8*)(Bs + boff[st][j]);
                acc[j] = __builtin_amdgcn_mfma_f32_16x16x32_bf16(af, bfr, acc[j],
                                                                 0, 0, 0);
            }
        }
        __syncthreads();
    }

    // epilogue: C 16x256; row=q*4+r, col=wn+j*16+ml; scale by dinv (from adj_s)
#pragma unroll
    for (int j = 0; j < 4; j++) {
        int gc = wn + j * 16 + ml;
#pragma unroll
        for (int r = 0; r < 4; r++) {
            int lrow = q * 4 + r;
            int grow = row0 + lrow;
            if (grow < M) {
                float pd = __builtin_bit_cast(float, adj_s[lrow][0].y);
                g2[(size_t)grow * 256 + gc] = f2bf(pd * acc[j][r]);
            }
        }
    }
}

// Layer-2 aggregate over PRE-SCALED g2: out = relu(pd*(g[d]+sum g[s]) + b)
// g: [n][256] bf16 as uint2; one wave per node; cols preloaded once.
__global__ __launch_bounds__(64) void aggregate2(const uint2* __restrict__ g,
                                                 const int* __restrict__ deg,
                                                 const int* __restrict__ col_ell,
                                                 const int* __restrict__ ovf_cnt,
                                                 const int* __restrict__ ovf,
                                                 const float* __restrict__ dinv,
                                                 const float* __restrict__ bias,
                                                 float* __restrict__ out) {
    const int d = blockIdx.x, t = threadIdx.x;
    const int cnt = min(deg[d], MAXD);
    const float pd = dinv[d];
    const size_t base = (size_t)d * 64 + t;
    const int* cm = col_ell + (size_t)d * MAXD;

    int cv = 0;
    float wv = 0.0f;
    if (t < MAXD && t < cnt) {
        cv = cm[t];
        wv = 1.0f;
    }
    float4 b = *(const float4*)(bias + t * 4);

    uint2 us = g[base];
    float a0 = bf_lo(us.x), a1 = bf_hi(us.x);
    float a2 = bf_lo(us.y), a3 = bf_hi(us.y);  // self term

    for (int e0 = 0; e0 < cnt; e0 += 8) {
        uint2 u[8];
        float ws[8];
#pragma unroll
        for (int j = 0; j < 8; j++) {
            int s = __shfl(cv, e0 + j);
            ws[j] = __shfl(wv, e0 + j);
            u[j] = g[(size_t)s * 64 + t];
        }
#pragma unroll
        for (int j = 0; j < 8; j++) {
            a0 = fmaf(ws[j], bf_lo(u[j].x), a0);
            a1 = fmaf(ws[j], bf_hi(u[j].x), a1);
            a2 = fmaf(ws[j], bf_lo(u[j].y), a2);
            a3 = fmaf(ws[j], bf_hi(u[j].y), a3);
        }
    }
    int nov = *ovf_cnt;  // ~always 0
    for (int k = 0; k < nov; k++) {
        if (ovf[2 * k] == d) {
            uint2 u = g[(size_t)ovf[2 * k + 1] * 64 + t];
            a0 += bf_lo(u.x); a1 += bf_hi(u.x);
            a2 += bf_lo(u.y); a3 += bf_hi(u.y);
        }
    }
    float4 o;
    o.x = fmaxf(fmaf(pd, a0, b.x), 0.0f);
    o.y = fmaxf(fmaf(pd, a1, b.y), 0.0f);
    o.z = fmaxf(fmaf(pd, a2, b.z), 0.0f);
    o.w = fmaxf(fmaf(pd, a3, b.w), 0.0f);
    *(float4*)(out + (size_t)d * 256 + t * 4) = o;
}

extern "C" void kernel_launch(void* const* d_in, const int* in_sizes, int n_in,
                              void* d_out, int out_size, void* d_ws, size_t ws_size,
                              hipStream_t stream) {
    const float* x  = (const float*)d_in[0];
    const int*   ei = (const int*)d_in[1];   // int32 on device
    const float* W1 = (const float*)d_in[2];
    const float* b1 = (const float*)d_in[3];
    const float* W2 = (const float*)d_in[4];
    const float* b2 = (const float*)d_in[5];
    float* out = (float*)d_out;

    const int FIN = 512, FH = 512, FOUT = 256;
    const int n = in_sizes[0] / FIN;  // 20000
    const int e = in_sizes[1] / 2;    // 160000
    const int* src = ei;
    const int* dst = ei + e;

    auto align_up = [](size_t v) { return (v + 255) & ~(size_t)255; };
    char* w = (char*)d_ws;
    int*      deg     = (int*)w;                 // deg[n] + ovf_cnt adjacent
    int*      ovf_cnt = deg + n;
    w += align_up((size_t)(n + 1) * 4);
    float*    dinv    = (float*)w;    w += align_up((size_t)n * 4);
    int*      col_ell = (int*)w;      w += align_up((size_t)n * MAXD * 4);
    int*      ovf     = (int*)w;      w += align_up((size_t)2048 * 4);
    ushort_t* xb      = (ushort_t*)w; w += align_up((size_t)n * FIN * 2);
    ushort_t* w1t     = (ushort_t*)w; w += align_up((size_t)FH * FIN * 2);
    ushort_t* w2t     = (ushort_t*)w; w += align_up((size_t)FOUT * FH * 2);
    ushort_t* g       = (ushort_t*)w; w += align_up((size_t)n * FH * 2);   // x@W1
    ushort_t* g2      = (ushort_t*)w; w += align_up((size_t)n * FOUT * 2); // scaled h1@W2

    const int nb_n = (n + 255) / 256;
    const int nb_e = (e + 255) / 256;
    const long xcount = (long)n * FIN;
    const int nb_conv = (int)((xcount / 4 + 255) / 256);

    hipMemsetAsync(deg, 0, (size_t)(n + 1) * 4, stream);  // deg + ovf_cnt

    prep_fused<<<nb_e + nb_conv + 256 + 128, 256, 0, stream>>>(
        src, dst, deg, col_ell, ovf_cnt, ovf, e, nb_e,
        x, xb, xcount, nb_conv, W1, w1t, W2, w2t);

    // layer 1 GEMM (unscaled) + dinv tail blocks
    {
        const int mb = (n + 127) / 128;
        int gemm_blocks = (FH / 128) * mb;
        gemm_mfma<<<gemm_blocks + nb_n, 256, 0, stream>>>(
            xb, w1t, g, n, FH, FIN, FH / 128, gemm_blocks, deg, dinv, n);
    }
    // fused aggregate1 + layer-2 GEMM (writes pre-scaled g2), BM=16
    agg1gemm2<<<(n + 15) / 16, 256, 0, stream>>>(
        g, w2t, deg, col_ell, ovf_cnt, ovf, dinv, b1, g2, n);

    aggregate2<<<n, 64, 0, stream>>>((const uint2*)g2, deg, col_ell, ovf_cnt,
                                     ovf, dinv, b2, out);

    (void)ws_size; (void)n_in; (void)out_size;
}

// Round 5
// 183.967 us; speedup vs baseline: 1.0817x; 1.0362x over previous
//
#include <hip/hip_runtime.h>

// ---------------------------------------------------------------------------
// 2-layer GCN forward (PyG GCNConv) on MI355X, round 11.
//   out[d] = relu( p[d]*( sum_{s->d} p[s]*h[s] + p[d]*h[d] ) + b ),  h = x@W
// R11: agg1gemm2 v2 — fix R10's gather locality.
//  - R10 (measured 56.7us): kt-sliced gather visited each 1KB neighbor row
//    8x as 128B slivers -> L2/L3 refetch (FETCH 72.6MB = 3.5x logical) and
//    short latency bursts (Occ 21.6%, 1.5TB/s fabric).
//  - R11: single-phase full-row gather with 32-reg h1 accumulator per thread
//    (thread = (row, 32-feat chunk); 16 thr/row x 64B = full-row coalesced,
//    every line touched once, zero barriers in the gather). Then one As
//    write + 8 MFMA K-steps streaming Bs only. BM=32, 512 thr, 76.4KB LDS
//    -> 2 blocks/CU = 16 waves/CU. launch_bounds(512,4) caps VGPR at 128.
// Floor analysis: gather is L3-BW bound (~7TB/s, uniform-random graph);
// prep is HBM-bound; harness fill+restores ~58us of the timed window.
// ---------------------------------------------------------------------------

typedef __bf16 bf16x8 __attribute__((ext_vector_type(8)));
typedef float floatx4 __attribute__((ext_vector_type(4)));
typedef unsigned short ushort_t;
typedef unsigned int uint_t;

#define MAXD 32
#define CAP 34  // self + 32 ELL + pad-to-even (pads: ps=0, col=self -> hot)

__device__ inline ushort_t f2bf(float f) {  // RNE fp32 -> bf16 bits
    unsigned u = __builtin_bit_cast(unsigned, f);
    unsigned r = (u + 0x7FFFu + ((u >> 16) & 1u)) >> 16;
    return (ushort_t)r;
}
__device__ inline float bf_lo(uint_t u) { return __builtin_bit_cast(float, u << 16); }
__device__ inline float bf_hi(uint_t u) { return __builtin_bit_cast(float, u & 0xFFFF0000u); }
__device__ inline uint_t pk2(float lo, float hi) {
    return (uint_t)f2bf(lo) | ((uint_t)f2bf(hi) << 16);
}

// [K][N] fp32 -> [N][K] bf16, one 32x32 tile per block (256 thr)
__device__ inline void transpose_tile(const float* __restrict__ in,
                                      ushort_t* __restrict__ out,
                                      int K, int N, int k0, int n0,
                                      ushort_t (*tile)[33]) {
    int tx = threadIdx.x & 31, ty = threadIdx.x >> 5;  // ty 0..7
    for (int r = ty; r < 32; r += 8)
        tile[r][tx] = f2bf(in[(size_t)(k0 + r) * N + n0 + tx]);
    __syncthreads();
    for (int r = ty; r < 32; r += 8)
        out[(size_t)(n0 + r) * K + k0 + tx] = tile[tx][r];
}

// Fused preprocessing: edge pass (deg count + ELL fill) | x->bf16 | W1^T | W2^T
__global__ __launch_bounds__(256) void prep_fused(
    const int* __restrict__ src, const int* __restrict__ dst,
    int* __restrict__ deg, int* __restrict__ col_ell,
    int* __restrict__ ovf_cnt, int* __restrict__ ovf, int e, int nb_e,
    const float* __restrict__ x, ushort_t* __restrict__ xb, long xcount, int nb_conv,
    const float* __restrict__ W1, ushort_t* __restrict__ w1t,
    const float* __restrict__ W2, ushort_t* __restrict__ w2t) {
    __shared__ ushort_t tile[32][33];
    int b = blockIdx.x;
    if (b < nb_e) {
        int i = b * 256 + threadIdx.x;
        if (i < e) {
            int s = src[i], d = dst[i];
            int slot = atomicAdd(&deg[d], 1);
            if (slot < MAXD) {
                col_ell[d * MAXD + slot] = s;
            } else {
                int k = atomicAdd(ovf_cnt, 1);
                ovf[2 * k] = d;
                ovf[2 * k + 1] = s;
            }
        }
        return;
    }
    b -= nb_e;
    if (b < nb_conv) {
        long i = ((long)b * 256 + threadIdx.x) * 4;
        if (i < xcount) {
            float4 v = *(const float4*)(x + i);
            ushort4 o = make_ushort4(f2bf(v.x), f2bf(v.y), f2bf(v.z), f2bf(v.w));
            *(ushort4*)(xb + i) = o;
        }
        return;
    }
    b -= nb_conv;
    if (b < 256) {  // W1: K=512, N=512 -> 16x16 tiles
        transpose_tile(W1, w1t, 512, 512, (b >> 4) * 32, (b & 15) * 32, tile);
        return;
    }
    b -= 256;       // W2: K=512, N=256 -> 8x16 tiles
    transpose_tile(W2, w2t, 512, 256, (b >> 3) * 32, (b & 7) * 32, tile);
}

// Layer-1 GEMM (+ dinv tail blocks).
// C[r][c] = bf16( sum_k A[r][k]*BT[c][k] ),  A:[M][K], BT:[N][K] bf16.
// 128x128 tile, BK=64, 4 waves, 4x4 16x16x32 frags.
// LDS swizzle: position s (16B chunks, 8/row) holds global granule s^(r&7).
__global__ __launch_bounds__(256) void gemm_mfma(
    const ushort_t* __restrict__ A, const ushort_t* __restrict__ BT,
    ushort_t* __restrict__ C,
    int M, int N, int K, int nbx, int gemm_blocks,
    const int* __restrict__ deg, float* __restrict__ dinv_out, int n) {
    __shared__ __align__(16) ushort_t As[8192];  // 128 rows x 64 k
    __shared__ __align__(16) ushort_t Bs[8192];

    if ((int)blockIdx.x >= gemm_blocks) {  // ---- dinv tail ----
        int i = ((int)blockIdx.x - gemm_blocks) * 256 + threadIdx.x;
        if (i < n) dinv_out[i] = 1.0f / sqrtf((float)(deg[i] + 1));
        return;
    }

    const int bx = (int)blockIdx.x % nbx, by = (int)blockIdx.x / nbx;
    const int tid = threadIdx.x;
    const int w = tid >> 6, lane = tid & 63;
    const int q = lane >> 4, ml = lane & 15;
    const int wm = (w >> 1) * 64, wn = (w & 1) * 64;
    const int row0 = by * 128, col0 = bx * 128;

    // staging: lane L covers row sub = L>>3, granule gsw = (L&7)^((L>>3)&7)
    const int rr = lane >> 3;                  // 0..7
    const int gsw = (lane & 7) ^ (rr & 7);     // global k-granule (x8 ushorts)
    const ushort_t* ga[4];
    const ushort_t* gb[4];
    ushort_t* la[4];
    ushort_t* lb[4];
#pragma unroll
    for (int rp = 0; rp < 4; rp++) {
        int r = rp * 32 + w * 8 + rr;
        int gra = min(row0 + r, M - 1);
        ga[rp] = A + (size_t)gra * K + gsw * 8;
        gb[rp] = BT + (size_t)(col0 + r) * K + gsw * 8;
        la[rp] = As + rp * 2048 + w * 512;  // wave-uniform; HW adds lane*16B
        lb[rp] = Bs + rp * 2048 + w * 512;
    }

    // fragment read offsets (ushort idx): row_loc*64 + ((g ^ (ml&7))*8)
    const int sel = ml & 7;
    int aoff[2][4], boff[2][4];
#pragma unroll
    for (int st = 0; st < 2; st++)
#pragma unroll
        for (int i = 0; i < 4; i++) {
            int g = q + st * 4;
            aoff[st][i] = (wm + i * 16 + ml) * 64 + ((g ^ sel) << 3);
            boff[st][i] = (wn + i * 16 + ml) * 64 + ((g ^ sel) << 3);
        }

    floatx4 acc[4][4];
#pragma unroll
    for (int i = 0; i < 4; i++)
#pragma unroll
        for (int j = 0; j < 4; j++) acc[i][j] = (floatx4)0.0f;

    for (int kt = 0; kt < K; kt += 64) {
#pragma unroll
        for (int rp = 0; rp < 4; rp++) {
            __builtin_amdgcn_global_load_lds(
                (const __attribute__((address_space(1))) unsigned*)ga[rp],
                (__attribute__((address_space(3))) unsigned*)la[rp], 16, 0, 0);
            __builtin_amdgcn_global_load_lds(
                (const __attribute__((address_space(1))) unsigned*)gb[rp],
                (__attribute__((address_space(3))) unsigned*)lb[rp], 16, 0, 0);
            ga[rp] += 64; gb[rp] += 64;
        }
        __syncthreads();
#pragma unroll
        for (int st = 0; st < 2; st++) {
            bf16x8 af[4], bfr[4];
#pragma unroll
            for (int i = 0; i < 4; i++) {
                af[i] = *(const bf16x8*)(As + aoff[st][i]);
                bfr[i] = *(const bf16x8*)(Bs + boff[st][i]);
            }
#pragma unroll
            for (int i = 0; i < 4; i++)
#pragma unroll
                for (int j = 0; j < 4; j++)
                    acc[i][j] = __builtin_amdgcn_mfma_f32_16x16x32_bf16(
                        af[i], bfr[j], acc[i][j], 0, 0, 0);
        }
        __syncthreads();
    }

    // epilogue: C/D layout col=lane&15, row=q*4+reg  [m89/m91]; store bf16
#pragma unroll
    for (int i = 0; i < 4; i++) {
        int rbase = row0 + wm + i * 16 + q * 4;
#pragma unroll
        for (int j = 0; j < 4; j++) {
            int gc = col0 + wn + j * 16 + ml;
#pragma unroll
            for (int r = 0; r < 4; r++) {
                int gr = rbase + r;
                if (gr < M) C[(size_t)gr * N + gc] = f2bf(acc[i][j][r]);
            }
        }
    }
}

// FUSED aggregate1 + layer-2 GEMM, v2: full-row gather, reg accumulator.
// h1[r][k] = relu(pd_r*(pd_r*g[r][k] + sum ps*g[s][k]) + b1[k]).
// BM=32 rows, 512 thr (8 waves). Thread (r = t>>4, c = t&15) owns feats
// [c*32, c*32+32): per neighbor loads 64B contiguous (16 thr/row = full 1KB
// row, single visit), accumulates h1 in 32 regs -> one As write -> 8 MFMA
// K-steps streaming Bs (w2t, L2-resident). Waves: wm=(w>>2)*16, wn=(w&3)*64.
// g2[r][c] = bf16(dinv[r] * (h1 @ W2)[r][c])  (pre-scaled for agg2).
__global__ __launch_bounds__(512, 4) void agg1gemm2(
    const ushort_t* __restrict__ g,    // [n][512] bf16 (unscaled x@W1)
    const ushort_t* __restrict__ BT,   // w2t [256][512] bf16
    const int* __restrict__ deg, const int* __restrict__ col_ell,
    const int* __restrict__ ovf_cnt, const int* __restrict__ ovf,
    const float* __restrict__ dinv, const float* __restrict__ b1,
    ushort_t* __restrict__ g2, int M) {
    __shared__ __align__(16) ushort_t As[32 * 512];   // 32 KB (full-K h1 tile)
    __shared__ __align__(16) ushort_t Bs[256 * 64];   // 32 KB (per-kt B tile)
    __shared__ int2  adj_s[32][CAP];                  // 8.5 KB (.x=col,.y=ps)
    __shared__ float b1_s[512];                       //  2 KB
    __shared__ int   cnt_s[32];

    const int tid = threadIdx.x;
    const int w = tid >> 6, lane = tid & 63;
    const int q = lane >> 4, ml = lane & 15;
    const int wm = (w >> 2) * 16, wn = (w & 3) * 64;
    const int row0 = (int)blockIdx.x * 32;

    // ---- prologue: bias + adjacency (slot0=self/pd; pads col=self, ps=0) ----
    b1_s[tid] = b1[tid];
    {
        int r = tid >> 4, jj = tid & 15;   // 16 threads per row
        int rg = min(row0 + r, M - 1);
        int cnt = min(deg[rg], MAXD);
        const int* cm = col_ell + (size_t)rg * MAXD;
#pragma unroll
        for (int pass = 0; pass < 3; pass++) {
            int j = jj + pass * 16;
            if (j >= CAP) break;
            int2 a;
            if (j == 0) {
                a.x = rg;
                a.y = __builtin_bit_cast(int, dinv[rg]);
                cnt_s[r] = cnt + 1;
            } else {
                bool vld = (j - 1) < cnt;
                int c = vld ? cm[j - 1] : rg;   // pad: self row (hot), weight 0
                a.x = c;
                a.y = vld ? __builtin_bit_cast(int, dinv[c]) : 0;
            }
            adj_s[r][j] = a;
        }
    }
    const int nov = *ovf_cnt;  // ~always 0
    __syncthreads();

    // ---- B staging pointers (global_load_lds, proven swizzle) ----
    const int rr = lane >> 3;
    const int gsw = (lane & 7) ^ (rr & 7);
    const ushort_t* gb[4];
    ushort_t* lb[4];
#pragma unroll
    for (int rp = 0; rp < 4; rp++) {
        gb[rp] = BT + (size_t)(rp * 64 + w * 8 + rr) * 512 + gsw * 8;
        lb[rp] = Bs + (rp * 64 + w * 8) * 64;  // wave-uniform; HW adds lane*16B
    }
    // issue Bs stage for kt=0 now -> overlaps with the whole gather phase
#pragma unroll
    for (int rp = 0; rp < 4; rp++) {
        __builtin_amdgcn_global_load_lds(
            (const __attribute__((address_space(1))) unsigned*)gb[rp],
            (__attribute__((address_space(3))) unsigned*)lb[rp], 16, 0, 0);
        gb[rp] += 64;
    }

    // ---- gather phase: full-row, register h1 accumulator ----
    const int r = tid >> 4;    // 0..31
    const int c = tid & 15;    // feat chunk: feats [c*32, c*32+32)
    const int cntR = cnt_s[r];
    const float pdr = __builtin_bit_cast(float, adj_s[r][0].y);
    const int selfR = adj_s[r][0].x;

    float acc[32];
#pragma unroll
    for (int i = 0; i < 32; i++) acc[i] = 0.0f;

    for (int e0 = 0; e0 < cntR; e0 += 2) {
        int2 cp0 = adj_s[r][e0];
        int2 cp1 = adj_s[r][e0 + 1];
        float ps0 = __builtin_bit_cast(float, cp0.y);
        float ps1 = __builtin_bit_cast(float, cp1.y);
        const ushort_t* p0 = g + (size_t)cp0.x * 512 + c * 32;
        const ushort_t* p1 = g + (size_t)cp1.x * 512 + c * 32;
        uint4 u0[4], u1[4];
#pragma unroll
        for (int s = 0; s < 4; s++) u0[s] = *(const uint4*)(p0 + s * 8);
#pragma unroll
        for (int s = 0; s < 4; s++) u1[s] = *(const uint4*)(p1 + s * 8);
#pragma unroll
        for (int s = 0; s < 4; s++) {
            acc[s * 8 + 0] = fmaf(ps0, bf_lo(u0[s].x), acc[s * 8 + 0]);
            acc[s * 8 + 1] = fmaf(ps0, bf_hi(u0[s].x), acc[s * 8 + 1]);
            acc[s * 8 + 2] = fmaf(ps0, bf_lo(u0[s].y), acc[s * 8 + 2]);
            acc[s * 8 + 3] = fmaf(ps0, bf_hi(u0[s].y), acc[s * 8 + 3]);
            acc[s * 8 + 4] = fmaf(ps0, bf_lo(u0[s].z), acc[s * 8 + 4]);
            acc[s * 8 + 5] = fmaf(ps0, bf_hi(u0[s].z), acc[s * 8 + 5]);
            acc[s * 8 + 6] = fmaf(ps0, bf_lo(u0[s].w), acc[s * 8 + 6]);
            acc[s * 8 + 7] = fmaf(ps0, bf_hi(u0[s].w), acc[s * 8 + 7]);
        }
#pragma unroll
        for (int s = 0; s < 4; s++) {
            acc[s * 8 + 0] = fmaf(ps1, bf_lo(u1[s].x), acc[s * 8 + 0]);
            acc[s * 8 + 1] = fmaf(ps1, bf_hi(u1[s].x), acc[s * 8 + 1]);
            acc[s * 8 + 2] = fmaf(ps1, bf_lo(u1[s].y), acc[s * 8 + 2]);
            acc[s * 8 + 3] = fmaf(ps1, bf_hi(u1[s].y), acc[s * 8 + 3]);
            acc[s * 8 + 4] = fmaf(ps1, bf_lo(u1[s].z), acc[s * 8 + 4]);
            acc[s * 8 + 5] = fmaf(ps1, bf_hi(u1[s].z), acc[s * 8 + 5]);
            acc[s * 8 + 6] = fmaf(ps1, bf_lo(u1[s].w), acc[s * 8 + 6]);
            acc[s * 8 + 7] = fmaf(ps1, bf_hi(u1[s].w), acc[s * 8 + 7]);
        }
    }
    for (int k2 = 0; k2 < nov; k2++) {  // ~never taken
        if (ovf[2 * k2] == selfR) {
            int sI = ovf[2 * k2 + 1];
            float ps = dinv[sI];
            const ushort_t* p0 = g + (size_t)sI * 512 + c * 32;
#pragma unroll
            for (int s = 0; s < 4; s++) {
                uint4 u = *(const uint4*)(p0 + s * 8);
                acc[s * 8 + 0] = fmaf(ps, bf_lo(u.x), acc[s * 8 + 0]);
                acc[s * 8 + 1] = fmaf(ps, bf_hi(u.x), acc[s * 8 + 1]);
                acc[s * 8 + 2] = fmaf(ps, bf_lo(u.y), acc[s * 8 + 2]);
                acc[s * 8 + 3] = fmaf(ps, bf_hi(u.y), acc[s * 8 + 3]);
                acc[s * 8 + 4] = fmaf(ps, bf_lo(u.z), acc[s * 8 + 4]);
                acc[s * 8 + 5] = fmaf(ps, bf_hi(u.z), acc[s * 8 + 5]);
                acc[s * 8 + 6] = fmaf(ps, bf_lo(u.w), acc[s * 8 + 6]);
                acc[s * 8 + 7] = fmaf(ps, bf_hi(u.w), acc[s * 8 + 7]);
            }
        }
    }

    // ---- bias + relu + pack -> As (swizzled within 8-granule groups) ----
#pragma unroll
    for (int s = 0; s < 4; s++) {
        float4 b0 = *(const float4*)(b1_s + c * 32 + s * 8);
        float4 b1v = *(const float4*)(b1_s + c * 32 + s * 8 + 4);
        float h0 = fmaxf(fmaf(pdr, acc[s * 8 + 0], b0.x), 0.0f);
        float h1 = fmaxf(fmaf(pdr, acc[s * 8 + 1], b0.y), 0.0f);
        float h2 = fmaxf(fmaf(pdr, acc[s * 8 + 2], b0.z), 0.0f);
        float h3 = fmaxf(fmaf(pdr, acc[s * 8 + 3], b0.w), 0.0f);
        float h4 = fmaxf(fmaf(pdr, acc[s * 8 + 4], b1v.x), 0.0f);
        float h5 = fmaxf(fmaf(pdr, acc[s * 8 + 5], b1v.y), 0.0f);
        float h6 = fmaxf(fmaf(pdr, acc[s * 8 + 6], b1v.z), 0.0f);
        float h7 = fmaxf(fmaf(pdr, acc[s * 8 + 7], b1v.w), 0.0f);
        uint4 U;
        U.x = pk2(h0, h1);
        U.y = pk2(h2, h3);
        U.z = pk2(h4, h5);
        U.w = pk2(h6, h7);
        int gabs = c * 4 + s;
        int pos = (gabs & ~7) | ((gabs & 7) ^ (r & 7));
        *(uint4*)(As + r * 512 + pos * 8) = U;
    }

    // ---- MFMA phase: As fixed, stream Bs per kt ----
    const int sel = ml & 7;
    int aoffb[2], boff[2][4];
#pragma unroll
    for (int st = 0; st < 2; st++) {
        aoffb[st] = (wm + ml) * 512 + (((st * 4 + q) ^ sel) << 3);
#pragma unroll
        for (int i = 0; i < 4; i++)
            boff[st][i] = (wn + i * 16 + ml) * 64 + (((q + st * 4) ^ sel) << 3);
    }
    floatx4 accm[4];
#pragma unroll
    for (int j = 0; j < 4; j++) accm[j] = (floatx4)0.0f;

    for (int kt = 0; kt < 8; kt++) {
        __syncthreads();  // Bs[kt] staged (vmcnt drained) + As visible (kt=0)
#pragma unroll
        for (int st = 0; st < 2; st++) {
            bf16x8 af = *(const bf16x8*)(As + aoffb[st] + kt * 64);
#pragma unroll
            for (int j = 0; j < 4; j++) {
                bf16x8 bfr = *(const bf16x8*)(Bs + boff[st][j]);
                accm[j] = __builtin_amdgcn_mfma_f32_16x16x32_bf16(af, bfr,
                                                                  accm[j], 0, 0, 0);
            }
        }
        __syncthreads();  // all waves done reading Bs[kt]
        if (kt < 7) {
#pragma unroll
            for (int rp = 0; rp < 4; rp++) {
                __builtin_amdgcn_global_load_lds(
                    (const __attribute__((address_space(1))) unsigned*)gb[rp],
                    (__attribute__((address_space(3))) unsigned*)lb[rp], 16, 0, 0);
                gb[rp] += 64;
            }
        }
    }

    // epilogue: C 32x256; row=wm+q*4+r, col=wn+j*16+ml; scale by dinv
#pragma unroll
    for (int j = 0; j < 4; j++) {
        int gc = wn + j * 16 + ml;
#pragma unroll
        for (int rg = 0; rg < 4; rg++) {
            int lrow = wm + q * 4 + rg;
            int grow = row0 + lrow;
            if (grow < M) {
                float pd = __builtin_bit_cast(float, adj_s[lrow][0].y);
                g2[(size_t)grow * 256 + gc] = f2bf(pd * accm[j][rg]);
            }
        }
    }
}

// Layer-2 aggregate over PRE-SCALED g2: out = relu(pd*(g[d]+sum g[s]) + b)
// g: [n][256] bf16 as uint2; one wave per node; cols preloaded once.
__global__ __launch_bounds__(64) void aggregate2(const uint2* __restrict__ g,
                                                 const int* __restrict__ deg,
                                                 const int* __restrict__ col_ell,
                                                 const int* __restrict__ ovf_cnt,
                                                 const int* __restrict__ ovf,
                                                 const float* __restrict__ dinv,
                                                 const float* __restrict__ bias,
                                                 float* __restrict__ out) {
    const int d = blockIdx.x, t = threadIdx.x;
    const int cnt = min(deg[d], MAXD);
    const float pd = dinv[d];
    const size_t base = (size_t)d * 64 + t;
    const int* cm = col_ell + (size_t)d * MAXD;

    int cv = 0;
    float wv = 0.0f;
    if (t < MAXD && t < cnt) {
        cv = cm[t];
        wv = 1.0f;
    }
    float4 b = *(const float4*)(bias + t * 4);

    uint2 us = g[base];
    float a0 = bf_lo(us.x), a1 = bf_hi(us.x);
    float a2 = bf_lo(us.y), a3 = bf_hi(us.y);  // self term

    for (int e0 = 0; e0 < cnt; e0 += 8) {
        uint2 u[8];
        float ws[8];
#pragma unroll
        for (int j = 0; j < 8; j++) {
            int s = __shfl(cv, e0 + j);
            ws[j] = __shfl(wv, e0 + j);
            u[j] = g[(size_t)s * 64 + t];
        }
#pragma unroll
        for (int j = 0; j < 8; j++) {
            a0 = fmaf(ws[j], bf_lo(u[j].x), a0);
            a1 = fmaf(ws[j], bf_hi(u[j].x), a1);
            a2 = fmaf(ws[j], bf_lo(u[j].y), a2);
            a3 = fmaf(ws[j], bf_hi(u[j].y), a3);
        }
    }
    int nov = *ovf_cnt;  // ~always 0
    for (int k = 0; k < nov; k++) {
        if (ovf[2 * k] == d) {
            uint2 u = g[(size_t)ovf[2 * k + 1] * 64 + t];
            a0 += bf_lo(u.x); a1 += bf_hi(u.x);
            a2 += bf_lo(u.y); a3 += bf_hi(u.y);
        }
    }
    float4 o;
    o.x = fmaxf(fmaf(pd, a0, b.x), 0.0f);
    o.y = fmaxf(fmaf(pd, a1, b.y), 0.0f);
    o.z = fmaxf(fmaf(pd, a2, b.z), 0.0f);
    o.w = fmaxf(fmaf(pd, a3, b.w), 0.0f);
    *(float4*)(out + (size_t)d * 256 + t * 4) = o;
}

extern "C" void kernel_launch(void* const* d_in, const int* in_sizes, int n_in,
                              void* d_out, int out_size, void* d_ws, size_t ws_size,
                              hipStream_t stream) {
    const float* x  = (const float*)d_in[0];
    const int*   ei = (const int*)d_in[1];   // int32 on device
    const float* W1 = (const float*)d_in[2];
    const float* b1 = (const float*)d_in[3];
    const float* W2 = (const float*)d_in[4];
    const float* b2 = (const float*)d_in[5];
    float* out = (float*)d_out;

    const int FIN = 512, FH = 512, FOUT = 256;
    const int n = in_sizes[0] / FIN;  // 20000
    const int e = in_sizes[1] / 2;    // 160000
    const int* src = ei;
    const int* dst = ei + e;

    auto align_up = [](size_t v) { return (v + 255) & ~(size_t)255; };
    char* w = (char*)d_ws;
    int*      deg     = (int*)w;                 // deg[n] + ovf_cnt adjacent
    int*      ovf_cnt = deg + n;
    w += align_up((size_t)(n + 1) * 4);
    float*    dinv    = (float*)w;    w += align_up((size_t)n * 4);
    int*      col_ell = (int*)w;      w += align_up((size_t)n * MAXD * 4);
    int*      ovf     = (int*)w;      w += align_up((size_t)2048 * 4);
    ushort_t* xb      = (ushort_t*)w; w += align_up((size_t)n * FIN * 2);
    ushort_t* w1t     = (ushort_t*)w; w += align_up((size_t)FH * FIN * 2);
    ushort_t* w2t     = (ushort_t*)w; w += align_up((size_t)FOUT * FH * 2);
    ushort_t* g       = (ushort_t*)w; w += align_up((size_t)n * FH * 2);   // x@W1
    ushort_t* g2      = (ushort_t*)w; w += align_up((size_t)n * FOUT * 2); // scaled h1@W2

    const int nb_n = (n + 255) / 256;
    const int nb_e = (e + 255) / 256;
    const long xcount = (long)n * FIN;
    const int nb_conv = (int)((xcount / 4 + 255) / 256);

    hipMemsetAsync(deg, 0, (size_t)(n + 1) * 4, stream);  // deg + ovf_cnt

    prep_fused<<<nb_e + nb_conv + 256 + 128, 256, 0, stream>>>(
        src, dst, deg, col_ell, ovf_cnt, ovf, e, nb_e,
        x, xb, xcount, nb_conv, W1, w1t, W2, w2t);

    // layer 1 GEMM (unscaled) + dinv tail blocks
    {
        const int mb = (n + 127) / 128;
        int gemm_blocks = (FH / 128) * mb;
        gemm_mfma<<<gemm_blocks + nb_n, 256, 0, stream>>>(
            xb, w1t, g, n, FH, FIN, FH / 128, gemm_blocks, deg, dinv, n);
    }
    // fused aggregate1 + layer-2 GEMM (writes pre-scaled g2), BM=32, 512 thr
    agg1gemm2<<<(n + 31) / 32, 512, 0, stream>>>(
        g, w2t, deg, col_ell, ovf_cnt, ovf, dinv, b1, g2, n);

    aggregate2<<<n, 64, 0, stream>>>((const uint2*)g2, deg, col_ell, ovf_cnt,
                                     ovf, dinv, b2, out);

    (void)ws_size; (void)n_in; (void)out_size;
}

// Round 6
// 180.994 us; speedup vs baseline: 1.0994x; 1.0164x over previous
//
#include <hip/hip_runtime.h>

// ---------------------------------------------------------------------------
// 2-layer GCN forward (PyG GCNConv) on MI355X, round 12.
//   out[d] = relu( p[d]*( sum_{s->d} p[s]*h[s] + p[d]*h[d] ) + b ),  h = x@W
// R12: agg1gemm2 v3 — fix R11's two measured losses:
//  - R11 (45.5us): (a) wave covered 4 rows (16thr/row) -> block waits on
//    max(cnt) over 32 rows (~1.8x gather inflation, Poisson(8) stats);
//    (b) As-write swizzle was 8-way bank-conflicted (1.92M conflicts).
//  - R12: 64 thr/row, 1 row/wave/pass, 4 passes. Wave time ~ sum of 4 cnts
//    (1.2x inflation). Thread owns one 16B k-granule -> As write pos =
//    (c&~7)|((c&7)^(r&7)) is 2-way (free). Gather loads: 64 lanes x 16B =
//    1KB/row coalesced, single visit, reg accumulator (8 floats).
//  - MFMA phase / Bs staging / epilogue / numerics unchanged from R11.
// Floor analysis: balanced gather = 184MB logical ~26us; prep HBM-bound;
// harness fill+restores ~58us of the timed window.
// ---------------------------------------------------------------------------

typedef __bf16 bf16x8 __attribute__((ext_vector_type(8)));
typedef float floatx4 __attribute__((ext_vector_type(4)));
typedef unsigned short ushort_t;
typedef unsigned int uint_t;

#define MAXD 32
#define CAP 34  // self + 32 ELL + pad-to-even (pads: ps=0, col=self -> hot)

__device__ inline ushort_t f2bf(float f) {  // RNE fp32 -> bf16 bits
    unsigned u = __builtin_bit_cast(unsigned, f);
    unsigned r = (u + 0x7FFFu + ((u >> 16) & 1u)) >> 16;
    return (ushort_t)r;
}
__device__ inline float bf_lo(uint_t u) { return __builtin_bit_cast(float, u << 16); }
__device__ inline float bf_hi(uint_t u) { return __builtin_bit_cast(float, u & 0xFFFF0000u); }
__device__ inline uint_t pk2(float lo, float hi) {
    return (uint_t)f2bf(lo) | ((uint_t)f2bf(hi) << 16);
}

// [K][N] fp32 -> [N][K] bf16, one 32x32 tile per block (256 thr)
__device__ inline void transpose_tile(const float* __restrict__ in,
                                      ushort_t* __restrict__ out,
                                      int K, int N, int k0, int n0,
                                      ushort_t (*tile)[33]) {
    int tx = threadIdx.x & 31, ty = threadIdx.x >> 5;  // ty 0..7
    for (int r = ty; r < 32; r += 8)
        tile[r][tx] = f2bf(in[(size_t)(k0 + r) * N + n0 + tx]);
    __syncthreads();
    for (int r = ty; r < 32; r += 8)
        out[(size_t)(n0 + r) * K + k0 + tx] = tile[tx][r];
}

// Fused preprocessing: edge pass (deg count + ELL fill) | x->bf16 | W1^T | W2^T
__global__ __launch_bounds__(256) void prep_fused(
    const int* __restrict__ src, const int* __restrict__ dst,
    int* __restrict__ deg, int* __restrict__ col_ell,
    int* __restrict__ ovf_cnt, int* __restrict__ ovf, int e, int nb_e,
    const float* __restrict__ x, ushort_t* __restrict__ xb, long xcount, int nb_conv,
    const float* __restrict__ W1, ushort_t* __restrict__ w1t,
    const float* __restrict__ W2, ushort_t* __restrict__ w2t) {
    __shared__ ushort_t tile[32][33];
    int b = blockIdx.x;
    if (b < nb_e) {
        int i = b * 256 + threadIdx.x;
        if (i < e) {
            int s = src[i], d = dst[i];
            int slot = atomicAdd(&deg[d], 1);
            if (slot < MAXD) {
                col_ell[d * MAXD + slot] = s;
            } else {
                int k = atomicAdd(ovf_cnt, 1);
                ovf[2 * k] = d;
                ovf[2 * k + 1] = s;
            }
        }
        return;
    }
    b -= nb_e;
    if (b < nb_conv) {
        long i = ((long)b * 256 + threadIdx.x) * 4;
        if (i < xcount) {
            float4 v = *(const float4*)(x + i);
            ushort4 o = make_ushort4(f2bf(v.x), f2bf(v.y), f2bf(v.z), f2bf(v.w));
            *(ushort4*)(xb + i) = o;
        }
        return;
    }
    b -= nb_conv;
    if (b < 256) {  // W1: K=512, N=512 -> 16x16 tiles
        transpose_tile(W1, w1t, 512, 512, (b >> 4) * 32, (b & 15) * 32, tile);
        return;
    }
    b -= 256;       // W2: K=512, N=256 -> 8x16 tiles
    transpose_tile(W2, w2t, 512, 256, (b >> 3) * 32, (b & 7) * 32, tile);
}

// Layer-1 GEMM (+ dinv tail blocks).
// C[r][c] = bf16( sum_k A[r][k]*BT[c][k] ),  A:[M][K], BT:[N][K] bf16.
// 128x128 tile, BK=64, 4 waves, 4x4 16x16x32 frags.
// LDS swizzle: position s (16B chunks, 8/row) holds global granule s^(r&7).
__global__ __launch_bounds__(256) void gemm_mfma(
    const ushort_t* __restrict__ A, const ushort_t* __restrict__ BT,
    ushort_t* __restrict__ C,
    int M, int N, int K, int nbx, int gemm_blocks,
    const int* __restrict__ deg, float* __restrict__ dinv_out, int n) {
    __shared__ __align__(16) ushort_t As[8192];  // 128 rows x 64 k
    __shared__ __align__(16) ushort_t Bs[8192];

    if ((int)blockIdx.x >= gemm_blocks) {  // ---- dinv tail ----
        int i = ((int)blockIdx.x - gemm_blocks) * 256 + threadIdx.x;
        if (i < n) dinv_out[i] = 1.0f / sqrtf((float)(deg[i] + 1));
        return;
    }

    const int bx = (int)blockIdx.x % nbx, by = (int)blockIdx.x / nbx;
    const int tid = threadIdx.x;
    const int w = tid >> 6, lane = tid & 63;
    const int q = lane >> 4, ml = lane & 15;
    const int wm = (w >> 1) * 64, wn = (w & 1) * 64;
    const int row0 = by * 128, col0 = bx * 128;

    // staging: lane L covers row sub = L>>3, granule gsw = (L&7)^((L>>3)&7)
    const int rr = lane >> 3;                  // 0..7
    const int gsw = (lane & 7) ^ (rr & 7);     // global k-granule (x8 ushorts)
    const ushort_t* ga[4];
    const ushort_t* gb[4];
    ushort_t* la[4];
    ushort_t* lb[4];
#pragma unroll
    for (int rp = 0; rp < 4; rp++) {
        int r = rp * 32 + w * 8 + rr;
        int gra = min(row0 + r, M - 1);
        ga[rp] = A + (size_t)gra * K + gsw * 8;
        gb[rp] = BT + (size_t)(col0 + r) * K + gsw * 8;
        la[rp] = As + rp * 2048 + w * 512;  // wave-uniform; HW adds lane*16B
        lb[rp] = Bs + rp * 2048 + w * 512;
    }

    // fragment read offsets (ushort idx): row_loc*64 + ((g ^ (ml&7))*8)
    const int sel = ml & 7;
    int aoff[2][4], boff[2][4];
#pragma unroll
    for (int st = 0; st < 2; st++)
#pragma unroll
        for (int i = 0; i < 4; i++) {
            int g = q + st * 4;
            aoff[st][i] = (wm + i * 16 + ml) * 64 + ((g ^ sel) << 3);
            boff[st][i] = (wn + i * 16 + ml) * 64 + ((g ^ sel) << 3);
        }

    floatx4 acc[4][4];
#pragma unroll
    for (int i = 0; i < 4; i++)
#pragma unroll
        for (int j = 0; j < 4; j++) acc[i][j] = (floatx4)0.0f;

    for (int kt = 0; kt < K; kt += 64) {
#pragma unroll
        for (int rp = 0; rp < 4; rp++) {
            __builtin_amdgcn_global_load_lds(
                (const __attribute__((address_space(1))) unsigned*)ga[rp],
                (__attribute__((address_space(3))) unsigned*)la[rp], 16, 0, 0);
            __builtin_amdgcn_global_load_lds(
                (const __attribute__((address_space(1))) unsigned*)gb[rp],
                (__attribute__((address_space(3))) unsigned*)lb[rp], 16, 0, 0);
            ga[rp] += 64; gb[rp] += 64;
        }
        __syncthreads();
#pragma unroll
        for (int st = 0; st < 2; st++) {
            bf16x8 af[4], bfr[4];
#pragma unroll
            for (int i = 0; i < 4; i++) {
                af[i] = *(const bf16x8*)(As + aoff[st][i]);
                bfr[i] = *(const bf16x8*)(Bs + boff[st][i]);
            }
#pragma unroll
            for (int i = 0; i < 4; i++)
#pragma unroll
                for (int j = 0; j < 4; j++)
                    acc[i][j] = __builtin_amdgcn_mfma_f32_16x16x32_bf16(
                        af[i], bfr[j], acc[i][j], 0, 0, 0);
        }
        __syncthreads();
    }

    // epilogue: C/D layout col=lane&15, row=q*4+reg  [m89/m91]; store bf16
#pragma unroll
    for (int i = 0; i < 4; i++) {
        int rbase = row0 + wm + i * 16 + q * 4;
#pragma unroll
        for (int j = 0; j < 4; j++) {
            int gc = col0 + wn + j * 16 + ml;
#pragma unroll
            for (int r = 0; r < 4; r++) {
                int gr = rbase + r;
                if (gr < M) C[(size_t)gr * N + gc] = f2bf(acc[i][j][r]);
            }
        }
    }
}

// FUSED aggregate1 + layer-2 GEMM, v3: 1 row per wave per pass.
// h1[r][k] = relu(pd_r*(pd_r*g[r][k] + sum ps*g[s][k]) + b1[k]).
// BM=32 rows, 512 thr (8 waves). Pass p (0..3): wave w handles row p*8+w;
// thread granule c = tid&63 owns feats [c*8, c*8+8). Per neighbor the wave
// loads one full 1KB row coalesced (64 x 16B), single visit, accumulates in
// 8 regs. After each pass: bias+relu+pack -> one swizzled As uint4 write
// (2-way, free). Then 8 MFMA K-steps streaming Bs (w2t, L2-resident).
// g2[r][c] = bf16(dinv[r] * (h1 @ W2)[r][c])  (pre-scaled for agg2).
__global__ __launch_bounds__(512, 4) void agg1gemm2(
    const ushort_t* __restrict__ g,    // [n][512] bf16 (unscaled x@W1)
    const ushort_t* __restrict__ BT,   // w2t [256][512] bf16
    const int* __restrict__ deg, const int* __restrict__ col_ell,
    const int* __restrict__ ovf_cnt, const int* __restrict__ ovf,
    const float* __restrict__ dinv, const float* __restrict__ b1,
    ushort_t* __restrict__ g2, int M) {
    __shared__ __align__(16) ushort_t As[32 * 512];   // 32 KB (full-K h1 tile)
    __shared__ __align__(16) ushort_t Bs[256 * 64];   // 32 KB (per-kt B tile)
    __shared__ int2  adj_s[32][CAP];                  // 8.5 KB (.x=col,.y=ps)
    __shared__ float b1_s[512];                       //  2 KB
    __shared__ int   cnt_s[32];

    const int tid = threadIdx.x;
    const int w = tid >> 6, lane = tid & 63;
    const int q = lane >> 4, ml = lane & 15;
    const int wm = (w >> 2) * 16, wn = (w & 3) * 64;
    const int row0 = (int)blockIdx.x * 32;

    // ---- prologue: bias + adjacency (slot0=self/pd; pads col=self, ps=0) ----
    b1_s[tid] = b1[tid];
    {
        int r = tid >> 4, jj = tid & 15;   // 16 threads per row
        int rg = min(row0 + r, M - 1);
        int cnt = min(deg[rg], MAXD);
        const int* cm = col_ell + (size_t)rg * MAXD;
#pragma unroll
        for (int pass = 0; pass < 3; pass++) {
            int j = jj + pass * 16;
            if (j >= CAP) break;
            int2 a;
            if (j == 0) {
                a.x = rg;
                a.y = __builtin_bit_cast(int, dinv[rg]);
                cnt_s[r] = cnt + 1;
            } else {
                bool vld = (j - 1) < cnt;
                int c = vld ? cm[j - 1] : rg;   // pad: self row (hot), weight 0
                a.x = c;
                a.y = vld ? __builtin_bit_cast(int, dinv[c]) : 0;
            }
            adj_s[r][j] = a;
        }
    }
    const int nov = *ovf_cnt;  // ~always 0
    __syncthreads();

    // ---- B staging pointers (global_load_lds, proven swizzle) ----
    const int rr = lane >> 3;
    const int gsw = (lane & 7) ^ (rr & 7);
    const ushort_t* gb[4];
    ushort_t* lb[4];
#pragma unroll
    for (int rp = 0; rp < 4; rp++) {
        gb[rp] = BT + (size_t)(rp * 64 + w * 8 + rr) * 512 + gsw * 8;
        lb[rp] = Bs + (rp * 64 + w * 8) * 64;  // wave-uniform; HW adds lane*16B
    }
    // issue Bs stage for kt=0 now -> overlaps with the whole gather phase
#pragma unroll
    for (int rp = 0; rp < 4; rp++) {
        __builtin_amdgcn_global_load_lds(
            (const __attribute__((address_space(1))) unsigned*)gb[rp],
            (__attribute__((address_space(3))) unsigned*)lb[rp], 16, 0, 0);
        gb[rp] += 64;
    }

    // ---- gather phase: 1 row per wave per pass, reg h1 accumulator ----
    const int c = lane;        // k-granule 0..63 (feats c*8..c*8+7)
    const ushort_t* gc_ = g + c * 8;
    float4 bv0 = *(const float4*)(b1_s + c * 8);
    float4 bv1 = *(const float4*)(b1_s + c * 8 + 4);

#pragma unroll
    for (int p = 0; p < 4; p++) {
        const int rP = p * 8 + w;
        const int cntR = cnt_s[rP];
        const float pdr = __builtin_bit_cast(float, adj_s[rP][0].y);
        const int selfR = adj_s[rP][0].x;

        float a0 = 0.f, a1 = 0.f, a2 = 0.f, a3 = 0.f;
        float a4 = 0.f, a5 = 0.f, a6 = 0.f, a7 = 0.f;

        for (int e0 = 0; e0 < cntR; e0 += 2) {
            int2 cp0 = adj_s[rP][e0];
            int2 cp1 = adj_s[rP][e0 + 1];
            float ps0 = __builtin_bit_cast(float, cp0.y);
            float ps1 = __builtin_bit_cast(float, cp1.y);
            uint4 u0 = *(const uint4*)(gc_ + (size_t)cp0.x * 512);
            uint4 u1 = *(const uint4*)(gc_ + (size_t)cp1.x * 512);
            a0 = fmaf(ps0, bf_lo(u0.x), a0);
            a1 = fmaf(ps0, bf_hi(u0.x), a1);
            a2 = fmaf(ps0, bf_lo(u0.y), a2);
            a3 = fmaf(ps0, bf_hi(u0.y), a3);
            a4 = fmaf(ps0, bf_lo(u0.z), a4);
            a5 = fmaf(ps0, bf_hi(u0.z), a5);
            a6 = fmaf(ps0, bf_lo(u0.w), a6);
            a7 = fmaf(ps0, bf_hi(u0.w), a7);
            a0 = fmaf(ps1, bf_lo(u1.x), a0);
            a1 = fmaf(ps1, bf_hi(u1.x), a1);
            a2 = fmaf(ps1, bf_lo(u1.y), a2);
            a3 = fmaf(ps1, bf_hi(u1.y), a3);
            a4 = fmaf(ps1, bf_lo(u1.z), a4);
            a5 = fmaf(ps1, bf_hi(u1.z), a5);
            a6 = fmaf(ps1, bf_lo(u1.w), a6);
            a7 = fmaf(ps1, bf_hi(u1.w), a7);
        }
        for (int k2 = 0; k2 < nov; k2++) {  // ~never taken
            if (ovf[2 * k2] == selfR) {
                int sI = ovf[2 * k2 + 1];
                float ps = dinv[sI];
                uint4 u = *(const uint4*)(gc_ + (size_t)sI * 512);
                a0 = fmaf(ps, bf_lo(u.x), a0);
                a1 = fmaf(ps, bf_hi(u.x), a1);
                a2 = fmaf(ps, bf_lo(u.y), a2);
                a3 = fmaf(ps, bf_hi(u.y), a3);
                a4 = fmaf(ps, bf_lo(u.z), a4);
                a5 = fmaf(ps, bf_hi(u.z), a5);
                a6 = fmaf(ps, bf_lo(u.w), a6);
                a7 = fmaf(ps, bf_hi(u.w), a7);
            }
        }
        float h0 = fmaxf(fmaf(pdr, a0, bv0.x), 0.0f);
        float h1 = fmaxf(fmaf(pdr, a1, bv0.y), 0.0f);
        float h2 = fmaxf(fmaf(pdr, a2, bv0.z), 0.0f);
        float h3 = fmaxf(fmaf(pdr, a3, bv0.w), 0.0f);
        float h4 = fmaxf(fmaf(pdr, a4, bv1.x), 0.0f);
        float h5 = fmaxf(fmaf(pdr, a5, bv1.y), 0.0f);
        float h6 = fmaxf(fmaf(pdr, a6, bv1.z), 0.0f);
        float h7 = fmaxf(fmaf(pdr, a7, bv1.w), 0.0f);
        uint4 U;
        U.x = pk2(h0, h1);
        U.y = pk2(h2, h3);
        U.z = pk2(h4, h5);
        U.w = pk2(h6, h7);
        int pos = (c & ~7) | ((c & 7) ^ (rP & 7));
        *(uint4*)(As + rP * 512 + pos * 8) = U;  // 2-way -> conflict-free
    }

    // ---- MFMA phase: As fixed, stream Bs per kt ----
    const int sel = ml & 7;
    int aoffb[2], boff[2][4];
#pragma unroll
    for (int st = 0; st < 2; st++) {
        aoffb[st] = (wm + ml) * 512 + (((st * 4 + q) ^ sel) << 3);
#pragma unroll
        for (int i = 0; i < 4; i++)
            boff[st][i] = (wn + i * 16 + ml) * 64 + (((q + st * 4) ^ sel) << 3);
    }
    floatx4 accm[4];
#pragma unroll
    for (int j = 0; j < 4; j++) accm[j] = (floatx4)0.0f;

    for (int kt = 0; kt < 8; kt++) {
        __syncthreads();  // Bs[kt] staged (vmcnt drained) + As visible (kt=0)
#pragma unroll
        for (int st = 0; st < 2; st++) {
            bf16x8 af = *(const bf16x8*)(As + aoffb[st] + kt * 64);
#pragma unroll
            for (int j = 0; j < 4; j++) {
                bf16x8 bfr = *(const bf16x8*)(Bs + boff[st][j]);
                accm[j] = __builtin_amdgcn_mfma_f32_16x16x32_bf16(af, bfr,
                                                                  accm[j], 0, 0, 0);
            }
        }
        __syncthreads();  // all waves done reading Bs[kt]
        if (kt < 7) {
#pragma unroll
            for (int rp = 0; rp < 4; rp++) {
                __builtin_amdgcn_global_load_lds(
                    (const __attribute__((address_space(1))) unsigned*)gb[rp],
                    (__attribute__((address_space(3))) unsigned*)lb[rp], 16, 0, 0);
                gb[rp] += 64;
            }
        }
    }

    // epilogue: C 32x256; row=wm+q*4+r, col=wn+j*16+ml; scale by dinv
#pragma unroll
    for (int j = 0; j < 4; j++) {
        int gcx = wn + j * 16 + ml;
#pragma unroll
        for (int rg = 0; rg < 4; rg++) {
            int lrow = wm + q * 4 + rg;
            int grow = row0 + lrow;
            if (grow < M) {
                float pd = __builtin_bit_cast(float, adj_s[lrow][0].y);
                g2[(size_t)grow * 256 + gcx] = f2bf(pd * accm[j][rg]);
            }
        }
    }
}

// Layer-2 aggregate over PRE-SCALED g2: out = relu(pd*(g[d]+sum g[s]) + b)
// g: [n][256] bf16 as uint2; one wave per node; cols preloaded once.
__global__ __launch_bounds__(64) void aggregate2(const uint2* __restrict__ g,
                                                 const int* __restrict__ deg,
                                                 const int* __restrict__ col_ell,
                                                 const int* __restrict__ ovf_cnt,
                                                 const int* __restrict__ ovf,
                                                 const float* __restrict__ dinv,
                                                 const float* __restrict__ bias,
                                                 float* __restrict__ out) {
    const int d = blockIdx.x, t = threadIdx.x;
    const int cnt = min(deg[d], MAXD);
    const float pd = dinv[d];
    const size_t base = (size_t)d * 64 + t;
    const int* cm = col_ell + (size_t)d * MAXD;

    int cv = 0;
    float wv = 0.0f;
    if (t < MAXD && t < cnt) {
        cv = cm[t];
        wv = 1.0f;
    }
    float4 b = *(const float4*)(bias + t * 4);

    uint2 us = g[base];
    float a0 = bf_lo(us.x), a1 = bf_hi(us.x);
    float a2 = bf_lo(us.y), a3 = bf_hi(us.y);  // self term

    for (int e0 = 0; e0 < cnt; e0 += 8) {
        uint2 u[8];
        float ws[8];
#pragma unroll
        for (int j = 0; j < 8; j++) {
            int s = __shfl(cv, e0 + j);
            ws[j] = __shfl(wv, e0 + j);
            u[j] = g[(size_t)s * 64 + t];
        }
#pragma unroll
        for (int j = 0; j < 8; j++) {
            a0 = fmaf(ws[j], bf_lo(u[j].x), a0);
            a1 = fmaf(ws[j], bf_hi(u[j].x), a1);
            a2 = fmaf(ws[j], bf_lo(u[j].y), a2);
            a3 = fmaf(ws[j], bf_hi(u[j].y), a3);
        }
    }
    int nov = *ovf_cnt;  // ~always 0
    for (int k = 0; k < nov; k++) {
        if (ovf[2 * k] == d) {
            uint2 u = g[(size_t)ovf[2 * k + 1] * 64 + t];
            a0 += bf_lo(u.x); a1 += bf_hi(u.x);
            a2 += bf_lo(u.y); a3 += bf_hi(u.y);
        }
    }
    float4 o;
    o.x = fmaxf(fmaf(pd, a0, b.x), 0.0f);
    o.y = fmaxf(fmaf(pd, a1, b.y), 0.0f);
    o.z = fmaxf(fmaf(pd, a2, b.z), 0.0f);
    o.w = fmaxf(fmaf(pd, a3, b.w), 0.0f);
    *(float4*)(out + (size_t)d * 256 + t * 4) = o;
}

extern "C" void kernel_launch(void* const* d_in, const int* in_sizes, int n_in,
                              void* d_out, int out_size, void* d_ws, size_t ws_size,
                              hipStream_t stream) {
    const float* x  = (const float*)d_in[0];
    const int*   ei = (const int*)d_in[1];   // int32 on device
    const float* W1 = (const float*)d_in[2];
    const float* b1 = (const float*)d_in[3];
    const float* W2 = (const float*)d_in[4];
    const float* b2 = (const float*)d_in[5];
    float* out = (float*)d_out;

    const int FIN = 512, FH = 512, FOUT = 256;
    const int n = in_sizes[0] / FIN;  // 20000
    const int e = in_sizes[1] / 2;    // 160000
    const int* src = ei;
    const int* dst = ei + e;

    auto align_up = [](size_t v) { return (v + 255) & ~(size_t)255; };
    char* w = (char*)d_ws;
    int*      deg     = (int*)w;                 // deg[n] + ovf_cnt adjacent
    int*      ovf_cnt = deg + n;
    w += align_up((size_t)(n + 1) * 4);
    float*    dinv    = (float*)w;    w += align_up((size_t)n * 4);
    int*      col_ell = (int*)w;      w += align_up((size_t)n * MAXD * 4);
    int*      ovf     = (int*)w;      w += align_up((size_t)2048 * 4);
    ushort_t* xb      = (ushort_t*)w; w += align_up((size_t)n * FIN * 2);
    ushort_t* w1t     = (ushort_t*)w; w += align_up((size_t)FH * FIN * 2);
    ushort_t* w2t     = (ushort_t*)w; w += align_up((size_t)FOUT * FH * 2);
    ushort_t* g       = (ushort_t*)w; w += align_up((size_t)n * FH * 2);   // x@W1
    ushort_t* g2      = (ushort_t*)w; w += align_up((size_t)n * FOUT * 2); // scaled h1@W2

    const int nb_n = (n + 255) / 256;
    const int nb_e = (e + 255) / 256;
    const long xcount = (long)n * FIN;
    const int nb_conv = (int)((xcount / 4 + 255) / 256);

    hipMemsetAsync(deg, 0, (size_t)(n + 1) * 4, stream);  // deg + ovf_cnt

    prep_fused<<<nb_e + nb_conv + 256 + 128, 256, 0, stream>>>(
        src, dst, deg, col_ell, ovf_cnt, ovf, e, nb_e,
        x, xb, xcount, nb_conv, W1, w1t, W2, w2t);

    // layer 1 GEMM (unscaled) + dinv tail blocks
    {
        const int mb = (n + 127) / 128;
        int gemm_blocks = (FH / 128) * mb;
        gemm_mfma<<<gemm_blocks + nb_n, 256, 0, stream>>>(
            xb, w1t, g, n, FH, FIN, FH / 128, gemm_blocks, deg, dinv, n);
    }
    // fused aggregate1 + layer-2 GEMM (writes pre-scaled g2), BM=32, 512 thr
    agg1gemm2<<<(n + 31) / 32, 512, 0, stream>>>(
        g, w2t, deg, col_ell, ovf_cnt, ovf, dinv, b1, g2, n);

    aggregate2<<<n, 64, 0, stream>>>((const uint2*)g2, deg, col_ell, ovf_cnt,
                                     ovf, dinv, b2, out);

    (void)ws_size; (void)n_in; (void)out_size;
}